// Round 7
// baseline (859.847 us; speedup 1.0000x reference)
//
#include <hip/hip_runtime.h>
#include <hip/hip_bf16.h>

#define NN   20000
#define E1N  100000
#define E2N  100000
#define NEFF 220000                     /* effective edges (skip row>=n half of E3d) */
#define TILE 64
#define NBLK ((NEFF + TILE - 1) / TILE) /* 3438 */
#define NPAD (NBLK * TILE)              /* 220032 */
#define RBF_STEP   0.09523809523809523f /* 6/63 */
#define RBF_INV2W2 56.88888888888889f   /* 1/(2*(6/64)^2) */

typedef short  bf16x8 __attribute__((ext_vector_type(8)));
typedef float  f32x4  __attribute__((ext_vector_type(4)));

__device__ __forceinline__ float4 ld4(const float* p) {
    return *reinterpret_cast<const float4*>(p);
}
__device__ __forceinline__ ushort f2bf(float x) {
    __hip_bfloat16 h = __float2bfloat16(x);
    return *reinterpret_cast<ushort*>(&h);
}
__device__ __forceinline__ float env_of(float d) {
    float x = fminf(fmaxf(d * (1.0f / 6.0f), 0.0f), 1.0f);
    return 0.5f * (__cosf(3.14159265358979f * x) + 1.0f);
}

__device__ __forceinline__ int edge_row(int eid, const int* __restrict__ E2d_idx,
                                        const int* __restrict__ Edist_idx) {
    if (eid < E1N) return E2d_idx[eid];
    if (eid < E1N + NN) return eid - E1N;
    return Edist_idx[eid - E1N - NN];
}

// ---------------- sort pipeline ----------------
__global__ __launch_bounds__(256) void hist_kernel(
    const int* __restrict__ E2d_idx, const int* __restrict__ Edist_idx,
    int* __restrict__ hist) {
    int g = blockIdx.x * 256 + threadIdx.x;
    if (g < NEFF) atomicAdd(&hist[edge_row(g, E2d_idx, Edist_idx)], 1);
}

__global__ __launch_bounds__(1024) void scan_kernel(
    const int* __restrict__ hist, int* __restrict__ start, int* __restrict__ cursor) {
    __shared__ int buf[1024];
    __shared__ int carry;
    const int t = threadIdx.x;
    if (t == 0) carry = 0;
    __syncthreads();
    for (int chunk = 0; chunk < 20; ++chunk) {
        int idx = chunk * 1024 + t;
        int v = (idx < NN) ? hist[idx] : 0;
        buf[t] = v;
        __syncthreads();
        for (int off = 1; off < 1024; off <<= 1) {
            int x = (t >= off) ? buf[t - off] : 0;
            __syncthreads();
            buf[t] += x;
            __syncthreads();
        }
        int excl  = buf[t] - v;
        int cbase = carry;
        int tot   = buf[1023];
        if (idx <= NN) {
            start[idx] = cbase + excl;
            if (idx < NN) cursor[idx] = cbase + excl;
        }
        __syncthreads();
        if (t == 0) carry = cbase + tot;
        __syncthreads();
    }
}

__global__ __launch_bounds__(256) void scatter_kernel(
    const int* __restrict__ E2d_idx, const int* __restrict__ Edist_idx,
    int* __restrict__ cursor, int* __restrict__ order) {
    int g = blockIdx.x * 256 + threadIdx.x;
    if (g < NEFF) {
        int r = edge_row(g, E2d_idx, Edist_idx);
        int pos = atomicAdd(&cursor[r], 1);
        order[pos] = g;
    }
}

__global__ __launch_bounds__(64) void chunkrow_kernel(
    const int* __restrict__ order, const int* __restrict__ E2d_idx,
    const int* __restrict__ Edist_idx, int cap, int nch, int* __restrict__ chunk_r0) {
    int i = threadIdx.x;
    if (i < nch) {
        int p = i * cap;
        if (p >= NEFF) p = NEFF - 1;
        chunk_r0[i] = edge_row(order[p], E2d_idx, Edist_idx);
    }
}

// ---------------- meta: per-sorted-edge precompute ----------------
__global__ __launch_bounds__(256) void meta_kernel(
    const int* __restrict__ order, const int* __restrict__ E2d_idx,
    const int* __restrict__ Edist_idx, const float* __restrict__ Edist_val,
    const float* __restrict__ Z, const float* __restrict__ Z3d,
    int4* __restrict__ metaI, float4* __restrict__ metaF,
    float4* __restrict__ payloadU) {
    int g = blockIdx.x * 256 + threadIdx.x;
    if (g >= NPAD) return;
    int eid = (g < NEFF) ? order[g] : -1;
    int row, col, ty, e2 = 0; float dval = 0.f;
    if (eid < 0)             { ty = 1; row = -1; col = 0; }
    else if (eid < E1N)      { ty = 0; row = E2d_idx[eid]; col = E2d_idx[E1N + eid]; e2 = eid; }
    else if (eid < E1N + NN) { ty = 1; int jj = eid - E1N; row = jj; col = jj + NN; }
    else { ty = 2; int g2 = eid - E1N - NN;
           row = Edist_idx[g2]; col = Edist_idx[E2N + g2]; dval = Edist_val[g2]; }
    int rs = (row < 0) ? 0 : row;
    float prx = Z[rs * 3], pry = Z[rs * 3 + 1], prz = Z[rs * 3 + 2];
    float pcx, pcy, pcz;
    if (col < NN) { pcx = Z[col * 3]; pcy = Z[col * 3 + 1]; pcz = Z[col * 3 + 2]; }
    else { int c = col - NN; pcx = Z3d[c * 3]; pcy = Z3d[c * 3 + 1]; pcz = Z3d[c * 3 + 2]; }
    float dx = prx - pcx, dy = pry - pcy, dz = prz - pcz;
    float dist = sqrtf(dx * dx + dy * dy + dz * dz + 1e-8f);
    float inv = 1.0f / dist;
    int vcol = (col < NN) ? col : -1;
    metaI[g] = make_int4(col, row, ty, e2);
    metaF[g] = make_float4(dist, dval, env_of(dist), env_of(dval));
    if (row >= 0)
        payloadU[g] = make_float4(dx * inv, dy * inv, dz * inv, __int_as_float(vcol));
}

// ---------------- prep: folded/bf16 weights ----------------
__global__ __launch_bounds__(256) void prep_kernel(
    const float* __restrict__ W_phi1, const float* __restrict__ b_phi1,
    const float* __restrict__ W_e2d, const float* __restrict__ W_rbf,
    const float* __restrict__ W_phi2, const float* __restrict__ W_msg,
    const float* __restrict__ et,
    ushort* __restrict__ W1c, ushort* __restrict__ W2b,
    ushort* __restrict__ Wmb, float* __restrict__ b_type) {
    int g = blockIdx.x * 256 + threadIdx.x;
    if (g < 32768) {
        int n = g >> 8, k = g & 255;
        float v;
        if (k < 128) v = W_phi1[n * 288 + k];
        else {
            int kk = k - 128;
            const float* Wsel = (kk < 64) ? W_e2d : W_rbf;  // both (128,64)
            int j = kk & 63;
            float s = 0.f;
            for (int a = 0; a < 128; ++a) s += W_phi1[n * 288 + 128 + a] * Wsel[a * 64 + j];
            v = s;
        }
        W1c[n * 256 + k] = f2bf(v);
    } else if (g < 32768 + 49152) {
        int q = g - 32768; W2b[q] = f2bf(W_phi2[q]);
    } else if (g < 32768 + 49152 + 24576) {
        int q = g - 81920; Wmb[q] = f2bf(W_msg[q]);
    } else if (g < 32768 + 49152 + 24576 + 384) {
        int q = g - 106496; int ty = q >> 7, n = q & 127;
        float s = b_phi1[n];
        for (int a = 0; a < 32; ++a) s += W_phi1[n * 288 + 256 + a] * et[ty * 32 + a];
        b_type[q] = s;
    }
}

// ---------------- featT: transpose E2d_feat (64,E1N) -> bf16 (E1N,64) ----------------
__global__ __launch_bounds__(256) void featT_kernel(
    const float* __restrict__ feat, ushort* __restrict__ featTb) {
    __shared__ float tile[64][65];
    const int t = threadIdx.x;
    const int cbase = blockIdx.x * 64;
    for (int i = t; i < 64 * 64; i += 256) {
        int k = i >> 6, e = i & 63;
        tile[k][e] = (cbase + e < E1N) ? feat[(size_t)k * E1N + cbase + e] : 0.f;
    }
    __syncthreads();
    for (int i = t; i < 64 * 64; i += 256) {
        int e = i >> 6, k = i & 63;
        if (cbase + e < E1N) featTb[(size_t)(cbase + e) * 64 + k] = f2bf(tile[k][e]);
    }
}

// ---------------- nodes = concat([H||H2d, H||virt]) @ W_i.T (bf16 out) ----------------
__global__ __launch_bounds__(256) void nodes_kernel(
    const float* __restrict__ H, const float* __restrict__ H2d,
    const float* __restrict__ virt, const float* __restrict__ Wi,
    ushort* __restrict__ nodesb) {
    __shared__ float x[16][256];
    const int t = threadIdx.x;
    const int rbase = blockIdx.x * 16;

    for (int i = t; i < 16 * 64; i += 256) {
        int r = i >> 6, q = i & 63;
        int row = rbase + r;
        float4 v;
        if (row < NN) {
            v = (q < 32) ? ld4(H + row * 128 + q * 4) : ld4(H2d + row * 128 + (q - 32) * 4);
        } else {
            int rr = row - NN;
            v = (q < 32) ? ld4(H + rr * 128 + q * 4) : ld4(virt + (q - 32) * 4);
        }
        *reinterpret_cast<float4*>(&x[r][q * 4]) = v;
    }
    __syncthreads();

    const int j = t & 127;
    const int rg = t >> 7;
    float acc[8] = {0.f, 0.f, 0.f, 0.f, 0.f, 0.f, 0.f, 0.f};
    for (int k4 = 0; k4 < 64; ++k4) {
        float4 w = ld4(Wi + j * 256 + k4 * 4);
#pragma unroll
        for (int r = 0; r < 8; ++r) {
            float4 xv = *reinterpret_cast<const float4*>(&x[rg * 8 + r][k4 * 4]);
            acc[r] += w.x * xv.x + w.y * xv.y + w.z * xv.z + w.w * xv.w;
        }
    }
#pragma unroll
    for (int r = 0; r < 8; ++r)
        nodesb[(rbase + rg * 8 + r) * 128 + j] = f2bf(acc[r]);
}

// ---------------- stageA: build A1[cap][256] bf16 (linear, coalesced) ----------------
// One thread per 16-byte unit: e = g>>5, u = g&31. Layout: k<128 nodes[col], k in
// [128,192) featT (ty0) else 0, k in [192,256) rbf(dval) (ty2) else 0.
__global__ __launch_bounds__(256) void stageA_kernel(
    const ushort* __restrict__ nodesb, const ushort* __restrict__ featTb,
    const int4* __restrict__ metaI, const float4* __restrict__ metaF,
    int p0, int ne, ushort* __restrict__ A1) {
    int g = blockIdx.x * 256 + threadIdx.x;
    int e = g >> 5, u = g & 31;
    if (e >= ne) return;
    int4 mi = metaI[p0 + e];
    uint4 val = make_uint4(0u, 0u, 0u, 0u);
    if (u < 16) {
        val = *reinterpret_cast<const uint4*>(nodesb + (size_t)mi.x * 128 + u * 8);
    } else if (mi.z == 0) {
        if (u < 24)
            val = *reinterpret_cast<const uint4*>(featTb + (size_t)mi.w * 64 + (u - 16) * 8);
    } else if (mi.z == 2 && u >= 24) {
        float4 mf = metaF[p0 + e];
        ushort tmp[8];
#pragma unroll
        for (int j = 0; j < 8; ++j) {
            float dd = mf.y - (float)((u - 24) * 8 + j) * RBF_STEP;
            tmp[j] = f2bf(__expf(-dd * dd * RBF_INV2W2) * mf.w);
        }
        val = *reinterpret_cast<const uint4*>(tmp);
    }
    *reinterpret_cast<uint4*>(A1 + (size_t)e * 256 + u * 8) = val;
}

// ---------------- gemm1: hid = silu(A1 @ W1c^T + b_ty) ----------------
__global__ __launch_bounds__(256, 4) void gemm1_kernel(
    const ushort* __restrict__ A1, const ushort* __restrict__ W1c,
    const float* __restrict__ b_type, const int4* __restrict__ metaI,
    int p0, ushort* __restrict__ hid) {
    __shared__ ushort WB[128][132];
    __shared__ float  s_bt[3][128];
    __shared__ int    s_ty[TILE];

    const int t = threadIdx.x;
    const int gbase = blockIdx.x * TILE;
    if (t < TILE) s_ty[t] = metaI[p0 + gbase + t].z;
    for (int i = t; i < 384; i += 256) ((float*)s_bt)[i] = b_type[i];
    for (int i = t; i < 128 * 16; i += 256) {      // WB <- W1c[:, 0:128]
        int n = i >> 4, q = i & 15;
        *reinterpret_cast<uint4*>(&WB[n][q * 8]) =
            *reinterpret_cast<const uint4*>(W1c + (size_t)n * 256 + q * 8);
    }
    __syncthreads();

    const int w  = t >> 6, lane = t & 63;
    const int mh = w >> 1, nh = w & 1;
    const int lr = lane >> 4, lc = lane & 15;
    const int ar0 = mh * 32 + lc;
    const ushort* Arow0 = A1 + (size_t)(gbase + ar0) * 256;
    const ushort* Arow1 = A1 + (size_t)(gbase + ar0 + 16) * 256;

    f32x4 acc[2][4];
#pragma unroll
    for (int mt = 0; mt < 2; ++mt)
#pragma unroll
        for (int nt = 0; nt < 4; ++nt) acc[mt][nt] = (f32x4){0.f, 0.f, 0.f, 0.f};
#pragma unroll
    for (int ks = 0; ks < 4; ++ks) {
        bf16x8 a0 = *reinterpret_cast<const bf16x8*>(Arow0 + ks * 32 + lr * 8);
        bf16x8 a1 = *reinterpret_cast<const bf16x8*>(Arow1 + ks * 32 + lr * 8);
#pragma unroll
        for (int nt = 0; nt < 4; ++nt) {
            int n = nh * 64 + nt * 16 + lc;
            bf16x8 b = *reinterpret_cast<const bf16x8*>(&WB[n][ks * 32 + lr * 8]);
            acc[0][nt] = __builtin_amdgcn_mfma_f32_16x16x32_bf16(a0, b, acc[0][nt], 0, 0, 0);
            acc[1][nt] = __builtin_amdgcn_mfma_f32_16x16x32_bf16(a1, b, acc[1][nt], 0, 0, 0);
        }
    }
    __syncthreads();
    for (int i = t; i < 128 * 16; i += 256) {      // WB <- W1c[:, 128:256]
        int n = i >> 4, q = i & 15;
        *reinterpret_cast<uint4*>(&WB[n][q * 8]) =
            *reinterpret_cast<const uint4*>(W1c + (size_t)n * 256 + 128 + q * 8);
    }
    __syncthreads();
#pragma unroll
    for (int ks = 4; ks < 8; ++ks) {
        bf16x8 a0 = *reinterpret_cast<const bf16x8*>(Arow0 + ks * 32 + lr * 8);
        bf16x8 a1 = *reinterpret_cast<const bf16x8*>(Arow1 + ks * 32 + lr * 8);
#pragma unroll
        for (int nt = 0; nt < 4; ++nt) {
            int n = nh * 64 + nt * 16 + lc;
            bf16x8 b = *reinterpret_cast<const bf16x8*>(&WB[n][(ks - 4) * 32 + lr * 8]);
            acc[0][nt] = __builtin_amdgcn_mfma_f32_16x16x32_bf16(a0, b, acc[0][nt], 0, 0, 0);
            acc[1][nt] = __builtin_amdgcn_mfma_f32_16x16x32_bf16(a1, b, acc[1][nt], 0, 0, 0);
        }
    }
#pragma unroll
    for (int mt = 0; mt < 2; ++mt)
#pragma unroll
        for (int nt = 0; nt < 4; ++nt)
#pragma unroll
            for (int r = 0; r < 4; ++r) {
                int e  = mh * 32 + mt * 16 + lr * 4 + r;
                int ch = nh * 64 + nt * 16 + lc;
                float x = acc[mt][nt][r] + s_bt[s_ty[e]][ch];
                hid[(size_t)(gbase + e) * 128 + ch] = f2bf(x / (1.0f + __expf(-x)));
            }
}

// ---------------- gemm2: payloadM = (hid@W2b^T + b2) * (rbf@Wmb^T + bm) ----------------
__global__ __launch_bounds__(256, 4) void gemm2_kernel(
    const ushort* __restrict__ hid, const ushort* __restrict__ W2b,
    const ushort* __restrict__ Wmb, const float* __restrict__ b_phi2,
    const float* __restrict__ b_msg, const int4* __restrict__ metaI,
    const float4* __restrict__ metaF, int p0, float* __restrict__ payloadM) {
    __shared__ ushort WB[128][132];
    __shared__ int    s_row[TILE];
    __shared__ float  s_dist[TILE], s_env[TILE];

    const int t = threadIdx.x;
    const int gbase = blockIdx.x * TILE;
    if (t < TILE) {
        s_row[t] = metaI[p0 + gbase + t].y;
        float4 mf = metaF[p0 + gbase + t];
        s_dist[t] = mf.x; s_env[t] = mf.z;
    }
    for (int i = t; i < 128 * 16; i += 256) {      // WB <- W2b c=0 slice
        int n = i >> 4, q = i & 15;
        *reinterpret_cast<uint4*>(&WB[n][q * 8]) =
            *reinterpret_cast<const uint4*>(W2b + (size_t)n * 128 + q * 8);
    }
    __syncthreads();

    const int w  = t >> 6, lane = t & 63;
    const int mh = w >> 1, nh = w & 1;
    const int lr = lane >> 4, lc = lane & 15;
    const int ar0 = mh * 32 + lc;
    const ushort* Hrow0 = hid + (size_t)(gbase + ar0) * 128;
    const ushort* Hrow1 = hid + (size_t)(gbase + ar0 + 16) * 128;

    // hoisted hid A-fragments (shared across the 3 c-chunks)
    bf16x8 ha0[4], ha1[4];
#pragma unroll
    for (int ks = 0; ks < 4; ++ks) {
        ha0[ks] = *reinterpret_cast<const bf16x8*>(Hrow0 + ks * 32 + lr * 8);
        ha1[ks] = *reinterpret_cast<const bf16x8*>(Hrow1 + ks * 32 + lr * 8);
    }
    // rbf(dist) A-fragments in-register
    bf16x8 ra0[2], ra1[2];
    {
        float dA = s_dist[ar0],      eA = s_env[ar0];
        float dB = s_dist[ar0 + 16], eB = s_env[ar0 + 16];
#pragma unroll
        for (int ks = 0; ks < 2; ++ks)
#pragma unroll
            for (int j = 0; j < 8; ++j) {
                float c  = (float)(ks * 32 + lr * 8 + j) * RBF_STEP;
                float tA = dA - c, tB = dB - c;
                ra0[ks][j] = (short)f2bf(__expf(-tA * tA * RBF_INV2W2) * eA);
                ra1[ks][j] = (short)f2bf(__expf(-tB * tB * RBF_INV2W2) * eB);
            }
    }

#pragma unroll
    for (int c = 0; c < 3; ++c) {
        f32x4 p[2][4], g[2][4];
#pragma unroll
        for (int mt = 0; mt < 2; ++mt)
#pragma unroll
            for (int nt = 0; nt < 4; ++nt) {
                p[mt][nt] = (f32x4){0.f, 0.f, 0.f, 0.f};
                g[mt][nt] = (f32x4){0.f, 0.f, 0.f, 0.f};
            }
#pragma unroll
        for (int ks = 0; ks < 4; ++ks) {
#pragma unroll
            for (int nt = 0; nt < 4; ++nt) {
                int n = nh * 64 + nt * 16 + lc;
                bf16x8 b = *reinterpret_cast<const bf16x8*>(&WB[n][ks * 32 + lr * 8]);
                p[0][nt] = __builtin_amdgcn_mfma_f32_16x16x32_bf16(ha0[ks], b, p[0][nt], 0, 0, 0);
                p[1][nt] = __builtin_amdgcn_mfma_f32_16x16x32_bf16(ha1[ks], b, p[1][nt], 0, 0, 0);
            }
        }
#pragma unroll
        for (int ks = 0; ks < 2; ++ks) {
#pragma unroll
            for (int nt = 0; nt < 4; ++nt) {
                int n = c * 128 + nh * 64 + nt * 16 + lc;
                bf16x8 b = *reinterpret_cast<const bf16x8*>(Wmb + (size_t)n * 64 + ks * 32 + lr * 8);
                g[0][nt] = __builtin_amdgcn_mfma_f32_16x16x32_bf16(ra0[ks], b, g[0][nt], 0, 0, 0);
                g[1][nt] = __builtin_amdgcn_mfma_f32_16x16x32_bf16(ra1[ks], b, g[1][nt], 0, 0, 0);
            }
        }
        __syncthreads();               // done reading WB for this c
        if (c < 2) {                   // stage next c's W2b slice (overlaps epilogue)
            for (int i = t; i < 128 * 16; i += 256) {
                int n = i >> 4, q = i & 15;
                *reinterpret_cast<uint4*>(&WB[n][q * 8]) =
                    *reinterpret_cast<const uint4*>(W2b + (size_t)((c + 1) * 128 + n) * 128 + q * 8);
            }
        }
#pragma unroll
        for (int mt = 0; mt < 2; ++mt)
#pragma unroll
            for (int nt = 0; nt < 4; ++nt) {
                int d  = nh * 64 + nt * 16 + lc;
                float b2 = b_phi2[c * 128 + d];
                float bm = b_msg[c * 128 + d];
#pragma unroll
                for (int r = 0; r < 4; ++r) {
                    int e = mh * 32 + mt * 16 + lr * 4 + r;
                    float m = (p[mt][nt][r] + b2) * (g[mt][nt][r] + bm);
                    if (s_row[e] >= 0)
                        payloadM[(size_t)(gbase + e) * 384 + c * 128 + d] = m;
                }
            }
        __syncthreads();               // WB(c+1) staged before next iteration reads it
    }
}

// ---------------- fallback: monolithic atomic edge kernel (MODE 0, r6-proven path) ----------------
__global__ __launch_bounds__(256, 2) void edge0_kernel(
    const ushort* __restrict__ nodesb, const float* __restrict__ V,
    const float* __restrict__ Z, const float* __restrict__ Z3d,
    const int* __restrict__ E2d_idx, const float* __restrict__ E2d_feat,
    const int* __restrict__ Edist_idx, const float* __restrict__ Edist_val,
    const ushort* __restrict__ W1c, const ushort* __restrict__ W2b,
    const ushort* __restrict__ Wmb, const float* __restrict__ b_type,
    const float* __restrict__ b_phi2, const float* __restrict__ b_msg,
    float* __restrict__ Hout, float* __restrict__ Vout) {

    __shared__ ushort A1[TILE][264];
    __shared__ float  s_bt[3][128];
    __shared__ int    s_row[TILE], s_col[TILE], s_ty[TILE], s_e2[TILE], s_vcol[TILE];
    __shared__ float  s_dist[TILE], s_dval[TILE], s_env[TILE], s_env2[TILE];
    __shared__ float  s_unit[TILE][3];
    ushort (*hid)[136] = reinterpret_cast<ushort(*)[136]>(&A1[0][0]);

    const int t = threadIdx.x;
    const int gbase = blockIdx.x * TILE;
    if (t < TILE) {
        int gpos = gbase + t;
        int eid = (gpos < NEFF) ? gpos : -1;
        int row, col, ty, e2 = 0; float dval = 0.f;
        if (eid < 0)             { ty = 1; row = -1; col = 0; }
        else if (eid < E1N)      { ty = 0; row = E2d_idx[eid]; col = E2d_idx[E1N + eid]; e2 = eid; }
        else if (eid < E1N + NN) { ty = 1; int jj = eid - E1N; row = jj; col = jj + NN; }
        else { ty = 2; int g2 = eid - E1N - NN;
               row = Edist_idx[g2]; col = Edist_idx[E2N + g2]; dval = Edist_val[g2]; }
        int rs = (row < 0) ? 0 : row;
        float prx = Z[rs * 3], pry = Z[rs * 3 + 1], prz = Z[rs * 3 + 2];
        float pcx, pcy, pcz;
        if (col < NN) { pcx = Z[col * 3]; pcy = Z[col * 3 + 1]; pcz = Z[col * 3 + 2]; }
        else { int c = col - NN; pcx = Z3d[c * 3]; pcy = Z3d[c * 3 + 1]; pcz = Z3d[c * 3 + 2]; }
        float dx = prx - pcx, dy = pry - pcy, dz = prz - pcz;
        float dist = sqrtf(dx * dx + dy * dy + dz * dz + 1e-8f);
        float inv = 1.0f / dist;
        s_row[t] = row; s_col[t] = col; s_ty[t] = ty; s_e2[t] = e2;
        s_vcol[t] = (col < NN) ? col : -1;
        s_unit[t][0] = dx * inv; s_unit[t][1] = dy * inv; s_unit[t][2] = dz * inv;
        s_dist[t] = dist; s_dval[t] = dval;
        s_env[t] = env_of(dist); s_env2[t] = env_of(dval);
    }
    for (int i = t; i < 384; i += 256) ((float*)s_bt)[i] = b_type[i];
    __syncthreads();

    for (int i = t; i < TILE * 16; i += 256) {
        int e = i >> 4, q = i & 15;
        *reinterpret_cast<uint4*>(&A1[e][q * 8]) =
            *reinterpret_cast<const uint4*>(nodesb + (size_t)s_col[e] * 128 + q * 8);
    }
    for (int i = t; i < TILE * 128; i += 256) {
        int k = i >> 6, e = i & 63;
        int ty = s_ty[e];
        float v = 0.f;
        if (ty == 0) { if (k < 64) v = E2d_feat[(size_t)k * E1N + s_e2[e]]; }
        else if (ty == 2) {
            if (k >= 64) {
                float dd = s_dval[e] - (float)(k - 64) * RBF_STEP;
                v = __expf(-dd * dd * RBF_INV2W2) * s_env2[e];
            }
        }
        A1[e][128 + k] = f2bf(v);
    }
    __syncthreads();

    const int w  = t >> 6, lane = t & 63;
    const int mh = w >> 1, nh = w & 1;
    const int lr = lane >> 4, lc = lane & 15;
    const int ar0 = mh * 32 + lc;

    bf16x8 ra0[2], ra1[2];
    {
        float dA = s_dist[ar0],      eA = s_env[ar0];
        float dB = s_dist[ar0 + 16], eB = s_env[ar0 + 16];
#pragma unroll
        for (int ks = 0; ks < 2; ++ks)
#pragma unroll
            for (int j = 0; j < 8; ++j) {
                float c  = (float)(ks * 32 + lr * 8 + j) * RBF_STEP;
                float tA = dA - c, tB = dB - c;
                ra0[ks][j] = (short)f2bf(__expf(-tA * tA * RBF_INV2W2) * eA);
                ra1[ks][j] = (short)f2bf(__expf(-tB * tB * RBF_INV2W2) * eB);
            }
    }

    f32x4 acc[2][4];
#pragma unroll
    for (int mt = 0; mt < 2; ++mt)
#pragma unroll
        for (int nt = 0; nt < 4; ++nt) acc[mt][nt] = (f32x4){0.f, 0.f, 0.f, 0.f};
#pragma unroll
    for (int ks = 0; ks < 8; ++ks) {
        bf16x8 a0 = *reinterpret_cast<const bf16x8*>(&A1[ar0][ks * 32 + lr * 8]);
        bf16x8 a1 = *reinterpret_cast<const bf16x8*>(&A1[ar0 + 16][ks * 32 + lr * 8]);
#pragma unroll
        for (int nt = 0; nt < 4; ++nt) {
            int n = nh * 64 + nt * 16 + lc;
            bf16x8 b = *reinterpret_cast<const bf16x8*>(W1c + (size_t)n * 256 + ks * 32 + lr * 8);
            acc[0][nt] = __builtin_amdgcn_mfma_f32_16x16x32_bf16(a0, b, acc[0][nt], 0, 0, 0);
            acc[1][nt] = __builtin_amdgcn_mfma_f32_16x16x32_bf16(a1, b, acc[1][nt], 0, 0, 0);
        }
    }
    __syncthreads();
#pragma unroll
    for (int mt = 0; mt < 2; ++mt)
#pragma unroll
        for (int nt = 0; nt < 4; ++nt)
#pragma unroll
            for (int r = 0; r < 4; ++r) {
                int e  = mh * 32 + mt * 16 + lr * 4 + r;
                int ch = nh * 64 + nt * 16 + lc;
                float x = acc[mt][nt][r] + s_bt[s_ty[e]][ch];
                hid[e][ch] = f2bf(x / (1.0f + __expf(-x)));
            }
    __syncthreads();

    f32x4 vgr[2][4];
#pragma unroll
    for (int c = 0; c < 3; ++c) {
        f32x4 p[2][4], g[2][4];
#pragma unroll
        for (int mt = 0; mt < 2; ++mt)
#pragma unroll
            for (int nt = 0; nt < 4; ++nt) {
                p[mt][nt] = (f32x4){0.f, 0.f, 0.f, 0.f};
                g[mt][nt] = (f32x4){0.f, 0.f, 0.f, 0.f};
            }
#pragma unroll
        for (int ks = 0; ks < 4; ++ks) {
            bf16x8 a0 = *reinterpret_cast<const bf16x8*>(&hid[ar0][ks * 32 + lr * 8]);
            bf16x8 a1 = *reinterpret_cast<const bf16x8*>(&hid[ar0 + 16][ks * 32 + lr * 8]);
#pragma unroll
            for (int nt = 0; nt < 4; ++nt) {
                int n = c * 128 + nh * 64 + nt * 16 + lc;
                bf16x8 b = *reinterpret_cast<const bf16x8*>(W2b + (size_t)n * 128 + ks * 32 + lr * 8);
                p[0][nt] = __builtin_amdgcn_mfma_f32_16x16x32_bf16(a0, b, p[0][nt], 0, 0, 0);
                p[1][nt] = __builtin_amdgcn_mfma_f32_16x16x32_bf16(a1, b, p[1][nt], 0, 0, 0);
            }
        }
#pragma unroll
        for (int ks = 0; ks < 2; ++ks) {
#pragma unroll
            for (int nt = 0; nt < 4; ++nt) {
                int n = c * 128 + nh * 64 + nt * 16 + lc;
                bf16x8 b = *reinterpret_cast<const bf16x8*>(Wmb + (size_t)n * 64 + ks * 32 + lr * 8);
                g[0][nt] = __builtin_amdgcn_mfma_f32_16x16x32_bf16(ra0[ks], b, g[0][nt], 0, 0, 0);
                g[1][nt] = __builtin_amdgcn_mfma_f32_16x16x32_bf16(ra1[ks], b, g[1][nt], 0, 0, 0);
            }
        }
#pragma unroll
        for (int mt = 0; mt < 2; ++mt)
#pragma unroll
            for (int nt = 0; nt < 4; ++nt) {
                int d  = nh * 64 + nt * 16 + lc;
                float b2 = b_phi2[c * 128 + d];
                float bm = b_msg[c * 128 + d];
#pragma unroll
                for (int r = 0; r < 4; ++r) {
                    int e = mh * 32 + mt * 16 + lr * 4 + r;
                    float m = (p[mt][nt][r] + b2) * (g[mt][nt][r] + bm);
                    int row = s_row[e];
                    if (c == 0) {
                        if (row >= 0) unsafeAtomicAdd(&Hout[(size_t)row * 128 + d], m);
                    } else if (c == 1) {
                        vgr[mt][nt][r] = m;
                    } else if (row >= 0) {
                        float vgv = vgr[mt][nt][r];
                        int vc = s_vcol[e];
                        float vx = 0.f, vy = 0.f, vz = 0.f;
                        if (vc >= 0) {
                            const float* vp = V + ((size_t)vc * 128 + d) * 3;
                            vx = vp[0]; vy = vp[1]; vz = vp[2];
                        }
                        float* vo = Vout + ((size_t)row * 128 + d) * 3;
                        unsafeAtomicAdd(vo + 0, vx * vgv + s_unit[e][0] * m);
                        unsafeAtomicAdd(vo + 1, vy * vgv + s_unit[e][1] * m);
                        unsafeAtomicAdd(vo + 2, vz * vgv + s_unit[e][2] * m);
                    }
                }
            }
    }
}

// ---------------- reduce: accumulate chunk payload into output (+V gather) ----------------
__global__ __launch_bounds__(256) void reduce_kernel(
    const float* __restrict__ payloadM, const float4* __restrict__ payloadU,
    const float* __restrict__ V, const int* __restrict__ start,
    const int* __restrict__ chunk_r0, int ci, int p0, int p1,
    float* __restrict__ Hout, float* __restrict__ Vout) {
    const int t = threadIdx.x;
    const int rbase = chunk_r0[ci] + blockIdx.x * 8;
    const bool hside = (t < 128);
    const int d = hside ? t : (t - 128);
    for (int nr = 0; nr < 8; ++nr) {
        int r = rbase + nr;
        if (r >= NN) return;
        int s0 = start[r], s1 = start[r + 1];
        if (s0 >= p1) return;
        int a = (s0 > p0) ? s0 : p0;
        int b = (s1 < p1) ? s1 : p1;
        if (a >= b) continue;
        if (hside) {
            float acc = 0.f;
            for (int i = a; i < b; ++i) acc += payloadM[(size_t)(i - p0) * 384 + d];
            float* ptr = &Hout[(size_t)r * 128 + d];
            float o = *ptr + acc;
            if (s1 <= p1) o = fminf(fmaxf(o, -100.f), 100.f);
            *ptr = o;
        } else {
            float ax = 0.f, ay = 0.f, az = 0.f;
            for (int i = a; i < b; ++i) {
                const float* pm = payloadM + (size_t)(i - p0) * 384;
                float vg = pm[128 + d], rg = pm[256 + d];
                float4 u = payloadU[i];
                int vc = __float_as_int(u.w);
                if (vc >= 0) {
                    const float* vp = V + (size_t)vc * 384 + d * 3;
                    ax += vg * vp[0]; ay += vg * vp[1]; az += vg * vp[2];
                }
                ax += rg * u.x; ay += rg * u.y; az += rg * u.z;
            }
            float* vo = Vout + (size_t)r * 384 + d * 3;
            float ox = vo[0] + ax, oy = vo[1] + ay, oz = vo[2] + az;
            if (s1 <= p1) {
                ox = fminf(fmaxf(ox, -100.f), 100.f);
                oy = fminf(fmaxf(oy, -100.f), 100.f);
                oz = fminf(fmaxf(oz, -100.f), 100.f);
            }
            vo[0] = ox; vo[1] = oy; vo[2] = oz;
        }
    }
}

extern "C" void kernel_launch(void* const* d_in, const int* in_sizes, int n_in,
                              void* d_out, int out_size, void* d_ws, size_t ws_size,
                              hipStream_t stream) {
    const float* H         = (const float*)d_in[0];
    const float* V         = (const float*)d_in[1];
    const float* Z         = (const float*)d_in[2];
    const float* H2d       = (const float*)d_in[4];
    const int*   E2d_idx   = (const int*)d_in[6];
    const float* E2d_feat  = (const float*)d_in[7];
    const float* Z3d       = (const float*)d_in[8];
    const int*   Edist_idx = (const int*)d_in[10];
    const float* Edist_val = (const float*)d_in[11];
    const float* virt      = (const float*)d_in[12];
    const float* et        = (const float*)d_in[13];
    const float* W_rbf     = (const float*)d_in[14];
    const float* W_e2d     = (const float*)d_in[15];
    const float* W_i       = (const float*)d_in[16];
    const float* W_phi1    = (const float*)d_in[17];
    const float* b_phi1    = (const float*)d_in[18];
    const float* W_phi2    = (const float*)d_in[19];
    const float* b_phi2    = (const float*)d_in[20];
    const float* W_msg     = (const float*)d_in[21];
    const float* b_msg     = (const float*)d_in[22];

    ushort* nodesb  = (ushort*)d_ws;                 // 40000*128 bf16
    ushort* W1c     = nodesb + 5120000;              // (128,256)
    ushort* W2b     = W1c + 32768;                   // (384,128)
    ushort* Wmb     = W2b + 49152;                   // (384,64)
    float*  b_type  = (float*)(Wmb + 24576);         // (3,128)
    ushort* featTb  = (ushort*)(b_type + 384);       // (E1N,64) bf16 = 12.8 MB
    int*    hist    = (int*)(featTb + (size_t)E1N * 64);
    int*    cursor  = hist + NN;
    int*    start   = cursor + NN;                   // NN+1
    int*    order   = start + NN + 1;                // NPAD
    int*    chunk_r0= order + NPAD;                  // 64
    int4*   metaI   = (int4*)(((size_t)(chunk_r0 + 64) + 15) & ~(size_t)15);
    float4* metaF   = (float4*)(metaI + NPAD);
    float4* payloadU= metaF + NPAD;

    size_t fixed = (size_t)((char*)(payloadU + NPAD) - (char*)d_ws);
    size_t poff  = (fixed + 255) & ~(size_t)255;
    size_t avail = (ws_size > poff) ? (ws_size - poff) : 0;
    // per-edge chunk bytes: payloadM 1536 + A1 512 + hid 256 = 2304
    long long cap_ll = (long long)(avail / 2304) / TILE * TILE;
    int cap = (cap_ll > (long long)NPAD) ? NPAD : (int)cap_ll;
    const bool big = (cap >= 4096);
    float*  payloadM = (float*)((char*)d_ws + poff);
    ushort* A1c      = (ushort*)(payloadM + (size_t)cap * 384);
    ushort* hidc     = A1c + (size_t)cap * 256;

    float* Hout = (float*)d_out;
    float* Vout = Hout + (size_t)NN * 128;

    hipMemsetAsync(d_out, 0, (size_t)out_size * sizeof(float), stream);
    prep_kernel<<<(32768 + 49152 + 24576 + 384 + 255) / 256, 256, 0, stream>>>(
        W_phi1, b_phi1, W_e2d, W_rbf, W_phi2, W_msg, et, W1c, W2b, Wmb, b_type);
    nodes_kernel<<<(2 * NN) / 16, 256, 0, stream>>>(H, H2d, virt, W_i, nodesb);

    if (big) {
        hipMemsetAsync(hist, 0, NN * sizeof(int), stream);
        featT_kernel<<<(E1N + 63) / 64, 256, 0, stream>>>(E2d_feat, featTb);
        hist_kernel<<<(NEFF + 255) / 256, 256, 0, stream>>>(E2d_idx, Edist_idx, hist);
        scan_kernel<<<1, 1024, 0, stream>>>(hist, start, cursor);
        scatter_kernel<<<(NEFF + 255) / 256, 256, 0, stream>>>(E2d_idx, Edist_idx, cursor, order);
        meta_kernel<<<(NPAD + 255) / 256, 256, 0, stream>>>(
            order, E2d_idx, Edist_idx, Edist_val, Z, Z3d, metaI, metaF, payloadU);
        int bpc = cap / TILE;
        int nch = (NBLK + bpc - 1) / bpc;
        chunkrow_kernel<<<1, 64, 0, stream>>>(order, E2d_idx, Edist_idx, cap, nch, chunk_r0);
        int rbound = (NN < cap + 1) ? NN : (cap + 1);
        int rgrid  = (rbound + 7) / 8;
        for (int ci = 0; ci < nch; ++ci) {
            int b0 = ci * bpc;
            int nb = ((NBLK - b0) < bpc) ? (NBLK - b0) : bpc;
            int p0 = b0 * TILE;
            int p1 = p0 + nb * TILE; if (p1 > NEFF) p1 = NEFF;
            int ne = nb * TILE;
            stageA_kernel<<<(ne * 32 + 255) / 256, 256, 0, stream>>>(
                nodesb, featTb, metaI, metaF, p0, ne, A1c);
            gemm1_kernel<<<nb, 256, 0, stream>>>(A1c, W1c, b_type, metaI, p0, hidc);
            gemm2_kernel<<<nb, 256, 0, stream>>>(hidc, W2b, Wmb, b_phi2, b_msg,
                                                 metaI, metaF, p0, payloadM);
            reduce_kernel<<<rgrid, 256, 0, stream>>>(payloadM, payloadU, V, start,
                                                     chunk_r0, ci, p0, p1, Hout, Vout);
        }
    } else {
        edge0_kernel<<<NBLK, 256, 0, stream>>>(
            nodesb, V, Z, Z3d, E2d_idx, E2d_feat, Edist_idx, Edist_val,
            W1c, W2b, Wmb, b_type, b_phi2, b_msg, Hout, Vout);
    }
}

// Round 8
// 481.945 us; speedup vs baseline: 1.7841x; 1.7841x over previous
//
#include <hip/hip_runtime.h>
#include <hip/hip_bf16.h>

#define NN   20000
#define E1N  100000
#define E2N  100000
#define NEFF 220000                     /* effective edges (skip row>=n half of E3d) */
#define TILE 64
#define NBLK ((NEFF + TILE - 1) / TILE) /* 3438 */
#define NPAD (NBLK * TILE)              /* 220032 */
#define RBF_STEP   0.09523809523809523f /* 6/63 */
#define RBF_INV2W2 56.88888888888889f   /* 1/(2*(6/64)^2) */

typedef short  bf16x8 __attribute__((ext_vector_type(8)));
typedef float  f32x4  __attribute__((ext_vector_type(4)));

__device__ __forceinline__ float4 ld4(const float* p) {
    return *reinterpret_cast<const float4*>(p);
}
__device__ __forceinline__ ushort f2bf(float x) {
    __hip_bfloat16 h = __float2bfloat16(x);
    return *reinterpret_cast<ushort*>(&h);
}
__device__ __forceinline__ float bf2f(ushort u) {
    return __uint_as_float(((unsigned)u) << 16);
}
__device__ __forceinline__ float env_of(float d) {
    float x = fminf(fmaxf(d * (1.0f / 6.0f), 0.0f), 1.0f);
    return 0.5f * (__cosf(3.14159265358979f * x) + 1.0f);
}

__device__ __forceinline__ int edge_row(int eid, const int* __restrict__ E2d_idx,
                                        const int* __restrict__ Edist_idx) {
    if (eid < E1N) return E2d_idx[eid];
    if (eid < E1N + NN) return eid - E1N;
    return Edist_idx[eid - E1N - NN];
}

// ---------------- sort pipeline ----------------
__global__ __launch_bounds__(256) void hist_kernel(
    const int* __restrict__ E2d_idx, const int* __restrict__ Edist_idx,
    int* __restrict__ hist) {
    int g = blockIdx.x * 256 + threadIdx.x;
    if (g < NEFF) atomicAdd(&hist[edge_row(g, E2d_idx, Edist_idx)], 1);
}

__global__ __launch_bounds__(1024) void scan_kernel(
    const int* __restrict__ hist, int* __restrict__ start, int* __restrict__ cursor) {
    __shared__ int buf[1024];
    __shared__ int carry;
    const int t = threadIdx.x;
    if (t == 0) carry = 0;
    __syncthreads();
    for (int chunk = 0; chunk < 20; ++chunk) {
        int idx = chunk * 1024 + t;
        int v = (idx < NN) ? hist[idx] : 0;
        buf[t] = v;
        __syncthreads();
        for (int off = 1; off < 1024; off <<= 1) {
            int x = (t >= off) ? buf[t - off] : 0;
            __syncthreads();
            buf[t] += x;
            __syncthreads();
        }
        int excl  = buf[t] - v;
        int cbase = carry;
        int tot   = buf[1023];
        if (idx <= NN) {
            start[idx] = cbase + excl;
            if (idx < NN) cursor[idx] = cbase + excl;
        }
        __syncthreads();
        if (t == 0) carry = cbase + tot;
        __syncthreads();
    }
}

__global__ __launch_bounds__(256) void scatter_kernel(
    const int* __restrict__ E2d_idx, const int* __restrict__ Edist_idx,
    int* __restrict__ cursor, int* __restrict__ order) {
    int g = blockIdx.x * 256 + threadIdx.x;
    if (g < NEFF) {
        int r = edge_row(g, E2d_idx, Edist_idx);
        int pos = atomicAdd(&cursor[r], 1);
        order[pos] = g;
    }
}

__global__ __launch_bounds__(64) void chunkrow_kernel(
    const int* __restrict__ order, const int* __restrict__ E2d_idx,
    const int* __restrict__ Edist_idx, int cap, int nch, int* __restrict__ chunk_r0) {
    int i = threadIdx.x;
    if (i < nch) {
        int p = i * cap;
        if (p >= NEFF) p = NEFF - 1;
        chunk_r0[i] = edge_row(order[p], E2d_idx, Edist_idx);
    }
}

// ---------------- meta: per-sorted-edge precompute ----------------
__global__ __launch_bounds__(256) void meta_kernel(
    const int* __restrict__ order, const int* __restrict__ E2d_idx,
    const int* __restrict__ Edist_idx, const float* __restrict__ Edist_val,
    const float* __restrict__ Z, const float* __restrict__ Z3d,
    int4* __restrict__ metaI, float4* __restrict__ metaF,
    float4* __restrict__ payloadU) {
    int g = blockIdx.x * 256 + threadIdx.x;
    if (g >= NPAD) return;
    int eid = (g < NEFF) ? order[g] : -1;
    int row, col, ty, e2 = 0; float dval = 0.f;
    if (eid < 0)             { ty = 1; row = -1; col = 0; }
    else if (eid < E1N)      { ty = 0; row = E2d_idx[eid]; col = E2d_idx[E1N + eid]; e2 = eid; }
    else if (eid < E1N + NN) { ty = 1; int jj = eid - E1N; row = jj; col = jj + NN; }
    else { ty = 2; int g2 = eid - E1N - NN;
           row = Edist_idx[g2]; col = Edist_idx[E2N + g2]; dval = Edist_val[g2]; }
    int rs = (row < 0) ? 0 : row;
    float prx = Z[rs * 3], pry = Z[rs * 3 + 1], prz = Z[rs * 3 + 2];
    float pcx, pcy, pcz;
    if (col < NN) { pcx = Z[col * 3]; pcy = Z[col * 3 + 1]; pcz = Z[col * 3 + 2]; }
    else { int c = col - NN; pcx = Z3d[c * 3]; pcy = Z3d[c * 3 + 1]; pcz = Z3d[c * 3 + 2]; }
    float dx = prx - pcx, dy = pry - pcy, dz = prz - pcz;
    float dist = sqrtf(dx * dx + dy * dy + dz * dz + 1e-8f);
    float inv = 1.0f / dist;
    int vcol = (col < NN) ? col : -1;
    metaI[g] = make_int4(col, row, ty, e2);
    metaF[g] = make_float4(dist, dval, env_of(dist), env_of(dval));
    if (row >= 0)
        payloadU[g] = make_float4(dx * inv, dy * inv, dz * inv, __int_as_float(vcol));
}

// ---------------- prep: folded/bf16 weights ----------------
__global__ __launch_bounds__(256) void prep_kernel(
    const float* __restrict__ W_phi1, const float* __restrict__ b_phi1,
    const float* __restrict__ W_e2d, const float* __restrict__ W_rbf,
    const float* __restrict__ W_phi2, const float* __restrict__ W_msg,
    const float* __restrict__ et,
    ushort* __restrict__ W1c, ushort* __restrict__ W2b,
    ushort* __restrict__ Wmb, float* __restrict__ b_type) {
    int g = blockIdx.x * 256 + threadIdx.x;
    if (g < 32768) {
        int n = g >> 8, k = g & 255;
        float v;
        if (k < 128) v = W_phi1[n * 288 + k];
        else {
            int kk = k - 128;
            const float* Wsel = (kk < 64) ? W_e2d : W_rbf;  // both (128,64)
            int j = kk & 63;
            float s = 0.f;
            for (int a = 0; a < 128; ++a) s += W_phi1[n * 288 + 128 + a] * Wsel[a * 64 + j];
            v = s;
        }
        W1c[n * 256 + k] = f2bf(v);
    } else if (g < 32768 + 49152) {
        int q = g - 32768; W2b[q] = f2bf(W_phi2[q]);
    } else if (g < 32768 + 49152 + 24576) {
        int q = g - 81920; Wmb[q] = f2bf(W_msg[q]);
    } else if (g < 32768 + 49152 + 24576 + 384) {
        int q = g - 106496; int ty = q >> 7, n = q & 127;
        float s = b_phi1[n];
        for (int a = 0; a < 32; ++a) s += W_phi1[n * 288 + 256 + a] * et[ty * 32 + a];
        b_type[q] = s;
    }
}

// ---------------- featT: transpose E2d_feat (64,E1N) -> bf16 (E1N,64) ----------------
__global__ __launch_bounds__(256) void featT_kernel(
    const float* __restrict__ feat, ushort* __restrict__ featTb) {
    __shared__ float tile[64][65];
    const int t = threadIdx.x;
    const int cbase = blockIdx.x * 64;
    for (int i = t; i < 64 * 64; i += 256) {
        int k = i >> 6, e = i & 63;
        tile[k][e] = (cbase + e < E1N) ? feat[(size_t)k * E1N + cbase + e] : 0.f;
    }
    __syncthreads();
    for (int i = t; i < 64 * 64; i += 256) {
        int e = i >> 6, k = i & 63;
        if (cbase + e < E1N) featTb[(size_t)(cbase + e) * 64 + k] = f2bf(tile[k][e]);
    }
}

// ---------------- nodes = concat([H||H2d, H||virt]) @ W_i.T (bf16 out) ----------------
__global__ __launch_bounds__(256) void nodes_kernel(
    const float* __restrict__ H, const float* __restrict__ H2d,
    const float* __restrict__ virt, const float* __restrict__ Wi,
    ushort* __restrict__ nodesb) {
    __shared__ float x[16][256];
    const int t = threadIdx.x;
    const int rbase = blockIdx.x * 16;

    for (int i = t; i < 16 * 64; i += 256) {
        int r = i >> 6, q = i & 63;
        int row = rbase + r;
        float4 v;
        if (row < NN) {
            v = (q < 32) ? ld4(H + row * 128 + q * 4) : ld4(H2d + row * 128 + (q - 32) * 4);
        } else {
            int rr = row - NN;
            v = (q < 32) ? ld4(H + rr * 128 + q * 4) : ld4(virt + (q - 32) * 4);
        }
        *reinterpret_cast<float4*>(&x[r][q * 4]) = v;
    }
    __syncthreads();

    const int j = t & 127;
    const int rg = t >> 7;
    float acc[8] = {0.f, 0.f, 0.f, 0.f, 0.f, 0.f, 0.f, 0.f};
    for (int k4 = 0; k4 < 64; ++k4) {
        float4 w = ld4(Wi + j * 256 + k4 * 4);
#pragma unroll
        for (int r = 0; r < 8; ++r) {
            float4 xv = *reinterpret_cast<const float4*>(&x[rg * 8 + r][k4 * 4]);
            acc[r] += w.x * xv.x + w.y * xv.y + w.z * xv.z + w.w * xv.w;
        }
    }
#pragma unroll
    for (int r = 0; r < 8; ++r)
        nodesb[(rbase + rg * 8 + r) * 128 + j] = f2bf(acc[r]);
}

// ---------------- fused MFMA edge pipeline, weights staged in LDS ----------------
// MODE 0: atomic scatter (fallback). MODE 1: sorted chunk + bf16 payload
// (m packed per-c in LDS, copied out with full-line 16B stores).
template <int MODE>
__global__ __launch_bounds__(256, 2) void edge_kernel(
    const ushort* __restrict__ nodesb, const float* __restrict__ V,
    const float* __restrict__ Z, const float* __restrict__ Z3d,
    const int* __restrict__ E2d_idx, const float* __restrict__ E2d_feat,
    const ushort* __restrict__ featTb,
    const int* __restrict__ Edist_idx, const float* __restrict__ Edist_val,
    const ushort* __restrict__ W1c, const ushort* __restrict__ W2b,
    const ushort* __restrict__ Wmb, const float* __restrict__ b_type,
    const float* __restrict__ b_phi2, const float* __restrict__ b_msg,
    const int4* __restrict__ metaI, const float4* __restrict__ metaF,
    int p0, ushort* __restrict__ payloadM,
    float* __restrict__ Hout, float* __restrict__ Vout) {

    __shared__ ushort A1[TILE][264];    // phi1 input K=256 (+8 pad); tail reused as hid + m_lds
    __shared__ ushort WB[128][132];     // staged weight tile
    __shared__ float  s_bt[3][128];
    __shared__ int    s_row[TILE], s_col[TILE], s_ty[TILE], s_e2[TILE], s_vcol[TILE];
    __shared__ float  s_dist[TILE], s_dval[TILE], s_env[TILE], s_env2[TILE];
    __shared__ float  s_unit[TILE][3];

    ushort (*hid)[136] = reinterpret_cast<ushort(*)[136]>(&A1[0][0]);   // 8704 ushorts
    ushort* m_lds = &A1[0][0] + 8704;                                    // 8192 ushorts = [64][128]

    const int t = threadIdx.x;
    const int gbase = blockIdx.x * TILE;   // chunk-local base

    // ---- edge meta ----
    if (MODE == 1) {
        if (t < TILE) {
            int4 mi = metaI[p0 + gbase + t];
            s_col[t] = mi.x; s_row[t] = mi.y; s_ty[t] = mi.z; s_e2[t] = mi.w;
        } else if (t < 2 * TILE) {
            int e = t - TILE;
            float4 mf = metaF[p0 + gbase + e];
            s_dist[e] = mf.x; s_dval[e] = mf.y; s_env[e] = mf.z; s_env2[e] = mf.w;
        }
    } else {
        if (t < TILE) {
            int gpos = gbase + t;
            int eid = (gpos < NEFF) ? gpos : -1;
            int row, col, ty, e2 = 0; float dval = 0.f;
            if (eid < 0)             { ty = 1; row = -1; col = 0; }
            else if (eid < E1N)      { ty = 0; row = E2d_idx[eid]; col = E2d_idx[E1N + eid]; e2 = eid; }
            else if (eid < E1N + NN) { ty = 1; int jj = eid - E1N; row = jj; col = jj + NN; }
            else { ty = 2; int g2 = eid - E1N - NN;
                   row = Edist_idx[g2]; col = Edist_idx[E2N + g2]; dval = Edist_val[g2]; }
            int rs = (row < 0) ? 0 : row;
            float prx = Z[rs * 3], pry = Z[rs * 3 + 1], prz = Z[rs * 3 + 2];
            float pcx, pcy, pcz;
            if (col < NN) { pcx = Z[col * 3]; pcy = Z[col * 3 + 1]; pcz = Z[col * 3 + 2]; }
            else { int c = col - NN; pcx = Z3d[c * 3]; pcy = Z3d[c * 3 + 1]; pcz = Z3d[c * 3 + 2]; }
            float dx = prx - pcx, dy = pry - pcy, dz = prz - pcz;
            float dist = sqrtf(dx * dx + dy * dy + dz * dz + 1e-8f);
            float inv = 1.0f / dist;
            s_row[t] = row; s_col[t] = col; s_ty[t] = ty; s_e2[t] = e2;
            s_vcol[t] = (col < NN) ? col : -1;
            s_unit[t][0] = dx * inv; s_unit[t][1] = dy * inv; s_unit[t][2] = dz * inv;
            s_dist[t] = dist; s_dval[t] = dval;
            s_env[t] = env_of(dist); s_env2[t] = env_of(dval);
        }
    }
    for (int i = t; i < 384; i += 256) ((float*)s_bt)[i] = b_type[i];
    __syncthreads();

    // ---- phase A: stage A1 = [nodes_bf16[col] | attr] and WB <- W1c K-half 0 ----
    for (int i = t; i < TILE * 16; i += 256) {     // left 128: 16B vector gather
        int e = i >> 4, q = i & 15;
        *reinterpret_cast<uint4*>(&A1[e][q * 8]) =
            *reinterpret_cast<const uint4*>(nodesb + (size_t)s_col[e] * 128 + q * 8);
    }
    if (MODE == 1) {
        for (int i = t; i < TILE * 128; i += 256) {  // right 128: [featT | rbf(dval)]
            int e = i >> 7, k = i & 127;
            int ty = s_ty[e];
            ushort v = 0;
            if (ty == 0) { if (k < 64) v = featTb[(size_t)s_e2[e] * 64 + k]; }
            else if (ty == 2) {
                if (k >= 64) {
                    float dd = s_dval[e] - (float)(k - 64) * RBF_STEP;
                    v = f2bf(__expf(-dd * dd * RBF_INV2W2) * s_env2[e]);
                }
            }
            A1[e][128 + k] = v;
        }
    } else {
        for (int i = t; i < TILE * 128; i += 256) {
            int k = i >> 6, e = i & 63;
            int ty = s_ty[e];
            float v = 0.f;
            if (ty == 0) { if (k < 64) v = E2d_feat[(size_t)k * E1N + s_e2[e]]; }
            else if (ty == 2) {
                if (k >= 64) {
                    float dd = s_dval[e] - (float)(k - 64) * RBF_STEP;
                    v = __expf(-dd * dd * RBF_INV2W2) * s_env2[e];
                }
            }
            A1[e][128 + k] = f2bf(v);
        }
    }
    for (int i = t; i < 128 * 16; i += 256) {      // WB <- W1c[:, 0:128]
        int n = i >> 4, q = i & 15;
        *reinterpret_cast<uint4*>(&WB[n][q * 8]) =
            *reinterpret_cast<const uint4*>(W1c + (size_t)n * 256 + q * 8);
    }
    __syncthreads();

    const int w  = t >> 6, lane = t & 63;
    const int mh = w >> 1, nh = w & 1;           // wave: 32 edges x 64 channels
    const int lr = lane >> 4, lc = lane & 15;
    const int ar0 = mh * 32 + lc;

    // ---- wd A-fragments in-register: rbf(dist) for edges ar0, ar0+16 ----
    bf16x8 ra0[2], ra1[2];   // [ks]
    {
        float dA = s_dist[ar0],      eA = s_env[ar0];
        float dB = s_dist[ar0 + 16], eB = s_env[ar0 + 16];
#pragma unroll
        for (int ks = 0; ks < 2; ++ks)
#pragma unroll
            for (int j = 0; j < 8; ++j) {
                float c  = (float)(ks * 32 + lr * 8 + j) * RBF_STEP;
                float tA = dA - c, tB = dB - c;
                ra0[ks][j] = (short)f2bf(__expf(-tA * tA * RBF_INV2W2) * eA);
                ra1[ks][j] = (short)f2bf(__expf(-tB * tB * RBF_INV2W2) * eB);
            }
    }

    // ---- phi1: (64 x 256) @ W1c^T -> silu -> hid bf16 (B staged in LDS, 2 halves) ----
    f32x4 acc[2][4];
#pragma unroll
    for (int mt = 0; mt < 2; ++mt)
#pragma unroll
        for (int nt = 0; nt < 4; ++nt) acc[mt][nt] = (f32x4){0.f, 0.f, 0.f, 0.f};
#pragma unroll
    for (int ks = 0; ks < 4; ++ks) {
        bf16x8 a0 = *reinterpret_cast<const bf16x8*>(&A1[ar0][ks * 32 + lr * 8]);
        bf16x8 a1 = *reinterpret_cast<const bf16x8*>(&A1[ar0 + 16][ks * 32 + lr * 8]);
#pragma unroll
        for (int nt = 0; nt < 4; ++nt) {
            int n = nh * 64 + nt * 16 + lc;
            bf16x8 b = *reinterpret_cast<const bf16x8*>(&WB[n][ks * 32 + lr * 8]);
            acc[0][nt] = __builtin_amdgcn_mfma_f32_16x16x32_bf16(a0, b, acc[0][nt], 0, 0, 0);
            acc[1][nt] = __builtin_amdgcn_mfma_f32_16x16x32_bf16(a1, b, acc[1][nt], 0, 0, 0);
        }
    }
    __syncthreads();
    for (int i = t; i < 128 * 16; i += 256) {      // WB <- W1c[:, 128:256]
        int n = i >> 4, q = i & 15;
        *reinterpret_cast<uint4*>(&WB[n][q * 8]) =
            *reinterpret_cast<const uint4*>(W1c + (size_t)n * 256 + 128 + q * 8);
    }
    __syncthreads();
#pragma unroll
    for (int ks = 4; ks < 8; ++ks) {
        bf16x8 a0 = *reinterpret_cast<const bf16x8*>(&A1[ar0][ks * 32 + lr * 8]);
        bf16x8 a1 = *reinterpret_cast<const bf16x8*>(&A1[ar0 + 16][ks * 32 + lr * 8]);
#pragma unroll
        for (int nt = 0; nt < 4; ++nt) {
            int n = nh * 64 + nt * 16 + lc;
            bf16x8 b = *reinterpret_cast<const bf16x8*>(&WB[n][(ks - 4) * 32 + lr * 8]);
            acc[0][nt] = __builtin_amdgcn_mfma_f32_16x16x32_bf16(a0, b, acc[0][nt], 0, 0, 0);
            acc[1][nt] = __builtin_amdgcn_mfma_f32_16x16x32_bf16(a1, b, acc[1][nt], 0, 0, 0);
        }
    }
    __syncthreads();   // all A1 + WB reads complete

    // ---- silu -> hid; stage WB <- W2b slice for c=0 ----
#pragma unroll
    for (int mt = 0; mt < 2; ++mt)
#pragma unroll
        for (int nt = 0; nt < 4; ++nt)
#pragma unroll
            for (int r = 0; r < 4; ++r) {
                int e  = mh * 32 + mt * 16 + lr * 4 + r;
                int ch = nh * 64 + nt * 16 + lc;
                float x = acc[mt][nt][r] + s_bt[s_ty[e]][ch];
                hid[e][ch] = f2bf(x / (1.0f + __expf(-x)));
            }
    for (int i = t; i < 128 * 16; i += 256) {
        int n = i >> 4, q = i & 15;
        *reinterpret_cast<uint4*>(&WB[n][q * 8]) =
            *reinterpret_cast<const uint4*>(W2b + (size_t)n * 128 + q * 8);
    }
    __syncthreads();

    // ---- hoist hid A-fragments to registers (shared across the 3 c-chunks) ----
    bf16x8 ha0[4], ha1[4];
#pragma unroll
    for (int ks = 0; ks < 4; ++ks) {
        ha0[ks] = *reinterpret_cast<const bf16x8*>(&hid[ar0][ks * 32 + lr * 8]);
        ha1[ks] = *reinterpret_cast<const bf16x8*>(&hid[ar0 + 16][ks * 32 + lr * 8]);
    }

    // ---- phi2 + wd in 3 channel-chunks of 128; m = phi*wd; emit ----
    f32x4 vgr[2][4];
#pragma unroll
    for (int c = 0; c < 3; ++c) {
        f32x4 p[2][4], g[2][4];
#pragma unroll
        for (int mt = 0; mt < 2; ++mt)
#pragma unroll
            for (int nt = 0; nt < 4; ++nt) {
                p[mt][nt] = (f32x4){0.f, 0.f, 0.f, 0.f};
                g[mt][nt] = (f32x4){0.f, 0.f, 0.f, 0.f};
            }
#pragma unroll
        for (int ks = 0; ks < 4; ++ks) {
#pragma unroll
            for (int nt = 0; nt < 4; ++nt) {
                int n = nh * 64 + nt * 16 + lc;
                bf16x8 b = *reinterpret_cast<const bf16x8*>(&WB[n][ks * 32 + lr * 8]);
                p[0][nt] = __builtin_amdgcn_mfma_f32_16x16x32_bf16(ha0[ks], b, p[0][nt], 0, 0, 0);
                p[1][nt] = __builtin_amdgcn_mfma_f32_16x16x32_bf16(ha1[ks], b, p[1][nt], 0, 0, 0);
            }
        }
#pragma unroll
        for (int ks = 0; ks < 2; ++ks) {
#pragma unroll
            for (int nt = 0; nt < 4; ++nt) {
                int n = c * 128 + nh * 64 + nt * 16 + lc;
                bf16x8 b = *reinterpret_cast<const bf16x8*>(Wmb + (size_t)n * 64 + ks * 32 + lr * 8);
                g[0][nt] = __builtin_amdgcn_mfma_f32_16x16x32_bf16(ra0[ks], b, g[0][nt], 0, 0, 0);
                g[1][nt] = __builtin_amdgcn_mfma_f32_16x16x32_bf16(ra1[ks], b, g[1][nt], 0, 0, 0);
            }
        }
        __syncthreads();               // WB reads for this c done; prev m_lds copy done
        if (c < 2) {                   // stage next c's W2b slice (overlaps epilogue)
            for (int i = t; i < 128 * 16; i += 256) {
                int n = i >> 4, q = i & 15;
                *reinterpret_cast<uint4*>(&WB[n][q * 8]) =
                    *reinterpret_cast<const uint4*>(W2b + (size_t)((c + 1) * 128 + n) * 128 + q * 8);
            }
        }
#pragma unroll
        for (int mt = 0; mt < 2; ++mt)
#pragma unroll
            for (int nt = 0; nt < 4; ++nt) {
                int d  = nh * 64 + nt * 16 + lc;
                float b2 = b_phi2[c * 128 + d];
                float bm = b_msg[c * 128 + d];
#pragma unroll
                for (int r = 0; r < 4; ++r) {
                    int e = mh * 32 + mt * 16 + lr * 4 + r;
                    float m = (p[mt][nt][r] + b2) * (g[mt][nt][r] + bm);
                    if (MODE == 1) {
                        m_lds[e * 128 + d] = f2bf(m);
                    } else {
                        int row = s_row[e];
                        if (c == 0) {
                            if (row >= 0) unsafeAtomicAdd(&Hout[(size_t)row * 128 + d], m);
                        } else if (c == 1) {
                            vgr[mt][nt][r] = m;
                        } else if (row >= 0) {
                            float vgv = vgr[mt][nt][r];
                            int vc = s_vcol[e];
                            float vx = 0.f, vy = 0.f, vz = 0.f;
                            if (vc >= 0) {
                                const float* vp = V + ((size_t)vc * 128 + d) * 3;
                                vx = vp[0]; vy = vp[1]; vz = vp[2];
                            }
                            float* vo = Vout + ((size_t)row * 128 + d) * 3;
                            unsafeAtomicAdd(vo + 0, vx * vgv + s_unit[e][0] * m);
                            unsafeAtomicAdd(vo + 1, vy * vgv + s_unit[e][1] * m);
                            unsafeAtomicAdd(vo + 2, vz * vgv + s_unit[e][2] * m);
                        }
                    }
                }
            }
        __syncthreads();               // m_lds complete + WB(c+1) staged
        if (MODE == 1) {
            // coalesced copy m_lds[64][128] bf16 -> payloadM rows (256B-aligned runs)
            for (int i = t; i < 1024; i += 256) {
                int e = i >> 4, q = i & 15;
                *reinterpret_cast<uint4*>(payloadM + (size_t)(gbase + e) * 384 + c * 128 + q * 8) =
                    *reinterpret_cast<const uint4*>(m_lds + e * 128 + q * 8);
            }
        }
    }
}

// ---------------- reduce: accumulate chunk payload into output (+V gather) ----------------
__global__ __launch_bounds__(256) void reduce_kernel(
    const ushort* __restrict__ payloadM, const float4* __restrict__ payloadU,
    const float* __restrict__ V, const int* __restrict__ start,
    const int* __restrict__ chunk_r0, int ci, int p0, int p1,
    float* __restrict__ Hout, float* __restrict__ Vout) {
    const int t = threadIdx.x;
    const int rbase = chunk_r0[ci] + blockIdx.x * 8;
    const bool hside = (t < 128);
    const int d = hside ? t : (t - 128);
    for (int nr = 0; nr < 8; ++nr) {
        int r = rbase + nr;
        if (r >= NN) return;
        int s0 = start[r], s1 = start[r + 1];
        if (s0 >= p1) return;
        int a = (s0 > p0) ? s0 : p0;
        int b = (s1 < p1) ? s1 : p1;
        if (a >= b) continue;
        if (hside) {
            float acc = 0.f;
            for (int i = a; i < b; ++i) acc += bf2f(payloadM[(size_t)(i - p0) * 384 + d]);
            float* ptr = &Hout[(size_t)r * 128 + d];
            float o = *ptr + acc;
            if (s1 <= p1) o = fminf(fmaxf(o, -100.f), 100.f);
            *ptr = o;
        } else {
            float ax = 0.f, ay = 0.f, az = 0.f;
            for (int i = a; i < b; ++i) {
                const ushort* pm = payloadM + (size_t)(i - p0) * 384;
                float vg = bf2f(pm[128 + d]), rg = bf2f(pm[256 + d]);
                float4 u = payloadU[i];
                int vc = __float_as_int(u.w);
                if (vc >= 0) {
                    const float* vp = V + (size_t)vc * 384 + d * 3;
                    ax += vg * vp[0]; ay += vg * vp[1]; az += vg * vp[2];
                }
                ax += rg * u.x; ay += rg * u.y; az += rg * u.z;
            }
            float* vo = Vout + (size_t)r * 384 + d * 3;
            float ox = vo[0] + ax, oy = vo[1] + ay, oz = vo[2] + az;
            if (s1 <= p1) {
                ox = fminf(fmaxf(ox, -100.f), 100.f);
                oy = fminf(fmaxf(oy, -100.f), 100.f);
                oz = fminf(fmaxf(oz, -100.f), 100.f);
            }
            vo[0] = ox; vo[1] = oy; vo[2] = oz;
        }
    }
}

extern "C" void kernel_launch(void* const* d_in, const int* in_sizes, int n_in,
                              void* d_out, int out_size, void* d_ws, size_t ws_size,
                              hipStream_t stream) {
    const float* H         = (const float*)d_in[0];
    const float* V         = (const float*)d_in[1];
    const float* Z         = (const float*)d_in[2];
    const float* H2d       = (const float*)d_in[4];
    const int*   E2d_idx   = (const int*)d_in[6];
    const float* E2d_feat  = (const float*)d_in[7];
    const float* Z3d       = (const float*)d_in[8];
    const int*   Edist_idx = (const int*)d_in[10];
    const float* Edist_val = (const float*)d_in[11];
    const float* virt      = (const float*)d_in[12];
    const float* et        = (const float*)d_in[13];
    const float* W_rbf     = (const float*)d_in[14];
    const float* W_e2d     = (const float*)d_in[15];
    const float* W_i       = (const float*)d_in[16];
    const float* W_phi1    = (const float*)d_in[17];
    const float* b_phi1    = (const float*)d_in[18];
    const float* W_phi2    = (const float*)d_in[19];
    const float* b_phi2    = (const float*)d_in[20];
    const float* W_msg     = (const float*)d_in[21];
    const float* b_msg     = (const float*)d_in[22];

    ushort* nodesb  = (ushort*)d_ws;                 // 40000*128 bf16
    ushort* W1c     = nodesb + 5120000;              // (128,256)
    ushort* W2b     = W1c + 32768;                   // (384,128)
    ushort* Wmb     = W2b + 49152;                   // (384,64)
    float*  b_type  = (float*)(Wmb + 24576);         // (3,128)
    ushort* featTb  = (ushort*)(b_type + 384);       // (E1N,64) bf16 = 12.8 MB
    int*    hist    = (int*)(featTb + (size_t)E1N * 64);
    int*    cursor  = hist + NN;
    int*    start   = cursor + NN;                   // NN+1
    int*    order   = start + NN + 1;                // NPAD
    int*    chunk_r0= order + NPAD;                  // 64
    int4*   metaI   = (int4*)(((size_t)(chunk_r0 + 64) + 15) & ~(size_t)15);
    float4* metaF   = (float4*)(metaI + NPAD);
    float4* payloadU= metaF + NPAD;

    size_t fixed = (size_t)((char*)(payloadU + NPAD) - (char*)d_ws);
    size_t poff  = (fixed + 255) & ~(size_t)255;
    size_t avail = (ws_size > poff) ? (ws_size - poff) : 0;
    long long cap_ll = (long long)(avail / 768) / TILE * TILE;   // 384 bf16 per edge
    int cap = (cap_ll > (long long)NPAD) ? NPAD : (int)cap_ll;
    const bool big = (cap >= 4096);
    ushort* payloadM = (ushort*)((char*)d_ws + poff);

    float* Hout = (float*)d_out;
    float* Vout = Hout + (size_t)NN * 128;

    hipMemsetAsync(d_out, 0, (size_t)out_size * sizeof(float), stream);
    prep_kernel<<<(32768 + 49152 + 24576 + 384 + 255) / 256, 256, 0, stream>>>(
        W_phi1, b_phi1, W_e2d, W_rbf, W_phi2, W_msg, et, W1c, W2b, Wmb, b_type);
    nodes_kernel<<<(2 * NN) / 16, 256, 0, stream>>>(H, H2d, virt, W_i, nodesb);

    if (big) {
        hipMemsetAsync(hist, 0, NN * sizeof(int), stream);
        featT_kernel<<<(E1N + 63) / 64, 256, 0, stream>>>(E2d_feat, featTb);
        hist_kernel<<<(NEFF + 255) / 256, 256, 0, stream>>>(E2d_idx, Edist_idx, hist);
        scan_kernel<<<1, 1024, 0, stream>>>(hist, start, cursor);
        scatter_kernel<<<(NEFF + 255) / 256, 256, 0, stream>>>(E2d_idx, Edist_idx, cursor, order);
        meta_kernel<<<(NPAD + 255) / 256, 256, 0, stream>>>(
            order, E2d_idx, Edist_idx, Edist_val, Z, Z3d, metaI, metaF, payloadU);
        int bpc = cap / TILE;
        int nch = (NBLK + bpc - 1) / bpc;
        chunkrow_kernel<<<1, 64, 0, stream>>>(order, E2d_idx, Edist_idx, cap, nch, chunk_r0);
        int rbound = (NN < cap + 1) ? NN : (cap + 1);
        int rgrid  = (rbound + 7) / 8;
        for (int ci = 0; ci < nch; ++ci) {
            int b0 = ci * bpc;
            int nb = ((NBLK - b0) < bpc) ? (NBLK - b0) : bpc;
            int p0 = b0 * TILE;
            int p1 = p0 + nb * TILE; if (p1 > NEFF) p1 = NEFF;
            edge_kernel<1><<<nb, 256, 0, stream>>>(
                nodesb, V, Z, Z3d, E2d_idx, E2d_feat, featTb, Edist_idx, Edist_val,
                W1c, W2b, Wmb, b_type, b_phi2, b_msg, metaI, metaF, p0, payloadM,
                Hout, Vout);
            reduce_kernel<<<rgrid, 256, 0, stream>>>(payloadM, payloadU, V, start,
                                                     chunk_r0, ci, p0, p1, Hout, Vout);
        }
    } else {
        edge_kernel<0><<<NBLK, 256, 0, stream>>>(
            nodesb, V, Z, Z3d, E2d_idx, E2d_feat, featTb, Edist_idx, Edist_val,
            W1c, W2b, Wmb, b_type, b_phi2, b_msg, metaI, metaF, 0, payloadM,
            Hout, Vout);
    }
}

// Round 9
// 405.151 us; speedup vs baseline: 2.1223x; 1.1895x over previous
//
#include <hip/hip_runtime.h>
#include <hip/hip_bf16.h>

#define NN   20000
#define E1N  100000
#define E2N  100000
#define NEFF 220000                     /* effective edges (skip row>=n half of E3d) */
#define TILE 64
#define NBLK ((NEFF + TILE - 1) / TILE) /* 3438 */
#define NPAD (NBLK * TILE)              /* 220032 */
#define RBF_STEP   0.09523809523809523f /* 6/63 */
#define RBF_INV2W2 56.88888888888889f   /* 1/(2*(6/64)^2) */

typedef short  bf16x8 __attribute__((ext_vector_type(8)));
typedef float  f32x4  __attribute__((ext_vector_type(4)));

__device__ __forceinline__ float4 ld4(const float* p) {
    return *reinterpret_cast<const float4*>(p);
}
__device__ __forceinline__ ushort f2bf(float x) {
    __hip_bfloat16 h = __float2bfloat16(x);
    return *reinterpret_cast<ushort*>(&h);
}
__device__ __forceinline__ float bf2f(ushort u) {
    return __uint_as_float(((unsigned)u) << 16);
}
__device__ __forceinline__ float env_of(float d) {
    float x = fminf(fmaxf(d * (1.0f / 6.0f), 0.0f), 1.0f);
    return 0.5f * (__cosf(3.14159265358979f * x) + 1.0f);
}

__device__ __forceinline__ int edge_row(int eid, const int* __restrict__ E2d_idx,
                                        const int* __restrict__ Edist_idx) {
    if (eid < E1N) return E2d_idx[eid];
    if (eid < E1N + NN) return eid - E1N;
    return Edist_idx[eid - E1N - NN];
}

// ---------------- sort pipeline ----------------
__global__ __launch_bounds__(256) void hist_kernel(
    const int* __restrict__ E2d_idx, const int* __restrict__ Edist_idx,
    int* __restrict__ hist) {
    int g = blockIdx.x * 256 + threadIdx.x;
    if (g < NEFF) atomicAdd(&hist[edge_row(g, E2d_idx, Edist_idx)], 1);
}

__global__ __launch_bounds__(1024) void scan_kernel(
    const int* __restrict__ hist, int* __restrict__ start, int* __restrict__ cursor) {
    __shared__ int buf[1024];
    __shared__ int carry;
    const int t = threadIdx.x;
    if (t == 0) carry = 0;
    __syncthreads();
    for (int chunk = 0; chunk < 20; ++chunk) {
        int idx = chunk * 1024 + t;
        int v = (idx < NN) ? hist[idx] : 0;
        buf[t] = v;
        __syncthreads();
        for (int off = 1; off < 1024; off <<= 1) {
            int x = (t >= off) ? buf[t - off] : 0;
            __syncthreads();
            buf[t] += x;
            __syncthreads();
        }
        int excl  = buf[t] - v;
        int cbase = carry;
        int tot   = buf[1023];
        if (idx <= NN) {
            start[idx] = cbase + excl;
            if (idx < NN) cursor[idx] = cbase + excl;
        }
        __syncthreads();
        if (t == 0) carry = cbase + tot;
        __syncthreads();
    }
}

__global__ __launch_bounds__(256) void scatter_kernel(
    const int* __restrict__ E2d_idx, const int* __restrict__ Edist_idx,
    int* __restrict__ cursor, int* __restrict__ order) {
    int g = blockIdx.x * 256 + threadIdx.x;
    if (g < NEFF) {
        int r = edge_row(g, E2d_idx, Edist_idx);
        int pos = atomicAdd(&cursor[r], 1);
        order[pos] = g;
    }
}

__global__ __launch_bounds__(64) void chunkrow_kernel(
    const int* __restrict__ order, const int* __restrict__ E2d_idx,
    const int* __restrict__ Edist_idx, int cap, int nch, int* __restrict__ chunk_r0) {
    int i = threadIdx.x;
    if (i < nch) {
        int p = i * cap;
        if (p >= NEFF) p = NEFF - 1;
        chunk_r0[i] = edge_row(order[p], E2d_idx, Edist_idx);
    }
}

// ---------------- meta: per-sorted-edge precompute ----------------
__global__ __launch_bounds__(256) void meta_kernel(
    const int* __restrict__ order, const int* __restrict__ E2d_idx,
    const int* __restrict__ Edist_idx, const float* __restrict__ Edist_val,
    const float* __restrict__ Z, const float* __restrict__ Z3d,
    int4* __restrict__ metaI, float4* __restrict__ metaF,
    float4* __restrict__ payloadU) {
    int g = blockIdx.x * 256 + threadIdx.x;
    if (g >= NPAD) return;
    int eid = (g < NEFF) ? order[g] : -1;
    int row, col, ty, e2 = 0; float dval = 0.f;
    if (eid < 0)             { ty = 1; row = -1; col = 0; }
    else if (eid < E1N)      { ty = 0; row = E2d_idx[eid]; col = E2d_idx[E1N + eid]; e2 = eid; }
    else if (eid < E1N + NN) { ty = 1; int jj = eid - E1N; row = jj; col = jj + NN; }
    else { ty = 2; int g2 = eid - E1N - NN;
           row = Edist_idx[g2]; col = Edist_idx[E2N + g2]; dval = Edist_val[g2]; }
    int rs = (row < 0) ? 0 : row;
    float prx = Z[rs * 3], pry = Z[rs * 3 + 1], prz = Z[rs * 3 + 2];
    float pcx, pcy, pcz;
    if (col < NN) { pcx = Z[col * 3]; pcy = Z[col * 3 + 1]; pcz = Z[col * 3 + 2]; }
    else { int c = col - NN; pcx = Z3d[c * 3]; pcy = Z3d[c * 3 + 1]; pcz = Z3d[c * 3 + 2]; }
    float dx = prx - pcx, dy = pry - pcy, dz = prz - pcz;
    float dist = sqrtf(dx * dx + dy * dy + dz * dz + 1e-8f);
    float inv = 1.0f / dist;
    int vcol = (col < NN) ? col : -1;
    metaI[g] = make_int4(col, row, ty, e2);
    metaF[g] = make_float4(dist, dval, env_of(dist), env_of(dval));
    if (row >= 0)
        payloadU[g] = make_float4(dx * inv, dy * inv, dz * inv, __int_as_float(vcol));
}

// ---------------- prep: folded/bf16 weights (+ Wib for nodes MFMA) ----------------
__global__ __launch_bounds__(256) void prep_kernel(
    const float* __restrict__ W_phi1, const float* __restrict__ b_phi1,
    const float* __restrict__ W_e2d, const float* __restrict__ W_rbf,
    const float* __restrict__ W_phi2, const float* __restrict__ W_msg,
    const float* __restrict__ et, const float* __restrict__ W_i,
    ushort* __restrict__ W1c, ushort* __restrict__ W2b,
    ushort* __restrict__ Wmb, float* __restrict__ b_type,
    ushort* __restrict__ Wib) {
    int g = blockIdx.x * 256 + threadIdx.x;
    if (g < 32768) {
        int n = g >> 8, k = g & 255;
        float v;
        if (k < 128) v = W_phi1[n * 288 + k];
        else {
            int kk = k - 128;
            const float* Wsel = (kk < 64) ? W_e2d : W_rbf;  // both (128,64)
            int j = kk & 63;
            float s = 0.f;
            for (int a = 0; a < 128; ++a) s += W_phi1[n * 288 + 128 + a] * Wsel[a * 64 + j];
            v = s;
        }
        W1c[n * 256 + k] = f2bf(v);
    } else if (g < 81920) {
        int q = g - 32768; W2b[q] = f2bf(W_phi2[q]);
    } else if (g < 106496) {
        int q = g - 81920; Wmb[q] = f2bf(W_msg[q]);
    } else if (g < 106880) {
        int q = g - 106496; int ty = q >> 7, n = q & 127;
        float s = b_phi1[n];
        for (int a = 0; a < 32; ++a) s += W_phi1[n * 288 + 256 + a] * et[ty * 32 + a];
        b_type[q] = s;
    } else if (g < 139648) {
        int q = g - 106880; Wib[q] = f2bf(W_i[q]);
    }
}

// ---------------- featT: transpose E2d_feat (64,E1N) -> bf16 (E1N,64) ----------------
__global__ __launch_bounds__(256) void featT_kernel(
    const float* __restrict__ feat, ushort* __restrict__ featTb) {
    __shared__ float tile[64][65];
    const int t = threadIdx.x;
    const int cbase = blockIdx.x * 64;
    for (int i = t; i < 64 * 64; i += 256) {
        int k = i >> 6, e = i & 63;
        tile[k][e] = (cbase + e < E1N) ? feat[(size_t)k * E1N + cbase + e] : 0.f;
    }
    __syncthreads();
    for (int i = t; i < 64 * 64; i += 256) {
        int e = i >> 6, k = i & 63;
        if (cbase + e < E1N) featTb[(size_t)(cbase + e) * 64 + k] = f2bf(tile[k][e]);
    }
}

// ---------------- nodes (MFMA): nodesb = bf16(concat([H||H2d, H||virt]) @ W_i.T) ----------------
__global__ __launch_bounds__(256, 2) void nodes_mfma_kernel(
    const float* __restrict__ H, const float* __restrict__ H2d,
    const float* __restrict__ virt, const ushort* __restrict__ Wib,
    ushort* __restrict__ nodesb) {
    __shared__ ushort A[64][264];
    __shared__ ushort WB[128][132];

    const int t = threadIdx.x;
    const int gbase = blockIdx.x * 64;

    for (int i = t; i < 64 * 64; i += 256) {   // stage A: f32 -> bf16
        int e = i >> 6, q = i & 63;            // q: group of 4 channels
        int row = gbase + e;
        float4 v;
        if (q < 32)          v = ld4(H + (size_t)((row < NN) ? row : row - NN) * 128 + q * 4);
        else if (row < NN)   v = ld4(H2d + (size_t)row * 128 + (q - 32) * 4);
        else                 v = ld4(virt + (q - 32) * 4);
        ushort tmp[4] = {f2bf(v.x), f2bf(v.y), f2bf(v.z), f2bf(v.w)};
        *reinterpret_cast<uint2*>(&A[e][q * 4]) = *reinterpret_cast<const uint2*>(tmp);
    }
    for (int i = t; i < 128 * 16; i += 256) {  // WB <- Wib[:, 0:128]
        int n = i >> 4, q = i & 15;
        *reinterpret_cast<uint4*>(&WB[n][q * 8]) =
            *reinterpret_cast<const uint4*>(Wib + (size_t)n * 256 + q * 8);
    }
    __syncthreads();

    const int w  = t >> 6, lane = t & 63;
    const int mh = w >> 1, nh = w & 1;
    const int lr = lane >> 4, lc = lane & 15;
    const int ar0 = mh * 32 + lc;

    f32x4 acc[2][4];
#pragma unroll
    for (int mt = 0; mt < 2; ++mt)
#pragma unroll
        for (int nt = 0; nt < 4; ++nt) acc[mt][nt] = (f32x4){0.f, 0.f, 0.f, 0.f};
#pragma unroll
    for (int ks = 0; ks < 4; ++ks) {
        bf16x8 a0 = *reinterpret_cast<const bf16x8*>(&A[ar0][ks * 32 + lr * 8]);
        bf16x8 a1 = *reinterpret_cast<const bf16x8*>(&A[ar0 + 16][ks * 32 + lr * 8]);
#pragma unroll
        for (int nt = 0; nt < 4; ++nt) {
            int n = nh * 64 + nt * 16 + lc;
            bf16x8 b = *reinterpret_cast<const bf16x8*>(&WB[n][ks * 32 + lr * 8]);
            acc[0][nt] = __builtin_amdgcn_mfma_f32_16x16x32_bf16(a0, b, acc[0][nt], 0, 0, 0);
            acc[1][nt] = __builtin_amdgcn_mfma_f32_16x16x32_bf16(a1, b, acc[1][nt], 0, 0, 0);
        }
    }
    __syncthreads();
    for (int i = t; i < 128 * 16; i += 256) {  // WB <- Wib[:, 128:256]
        int n = i >> 4, q = i & 15;
        *reinterpret_cast<uint4*>(&WB[n][q * 8]) =
            *reinterpret_cast<const uint4*>(Wib + (size_t)n * 256 + 128 + q * 8);
    }
    __syncthreads();
#pragma unroll
    for (int ks = 4; ks < 8; ++ks) {
        bf16x8 a0 = *reinterpret_cast<const bf16x8*>(&A[ar0][ks * 32 + lr * 8]);
        bf16x8 a1 = *reinterpret_cast<const bf16x8*>(&A[ar0 + 16][ks * 32 + lr * 8]);
#pragma unroll
        for (int nt = 0; nt < 4; ++nt) {
            int n = nh * 64 + nt * 16 + lc;
            bf16x8 b = *reinterpret_cast<const bf16x8*>(&WB[n][(ks - 4) * 32 + lr * 8]);
            acc[0][nt] = __builtin_amdgcn_mfma_f32_16x16x32_bf16(a0, b, acc[0][nt], 0, 0, 0);
            acc[1][nt] = __builtin_amdgcn_mfma_f32_16x16x32_bf16(a1, b, acc[1][nt], 0, 0, 0);
        }
    }
#pragma unroll
    for (int mt = 0; mt < 2; ++mt)
#pragma unroll
        for (int nt = 0; nt < 4; ++nt)
#pragma unroll
            for (int r = 0; r < 4; ++r) {
                int e  = mh * 32 + mt * 16 + lr * 4 + r;
                int ch = nh * 64 + nt * 16 + lc;
                nodesb[(size_t)(gbase + e) * 128 + ch] = f2bf(acc[mt][nt][r]);
            }
}

// ---------------- fused MFMA edge pipeline, weights staged in LDS ----------------
// MODE 0: atomic scatter (fallback). MODE 1: sorted chunk + bf16 payload.
template <int MODE>
__global__ __launch_bounds__(256, 2) void edge_kernel(
    const ushort* __restrict__ nodesb, const float* __restrict__ V,
    const float* __restrict__ Z, const float* __restrict__ Z3d,
    const int* __restrict__ E2d_idx, const float* __restrict__ E2d_feat,
    const ushort* __restrict__ featTb,
    const int* __restrict__ Edist_idx, const float* __restrict__ Edist_val,
    const ushort* __restrict__ W1c, const ushort* __restrict__ W2b,
    const ushort* __restrict__ Wmb, const float* __restrict__ b_type,
    const float* __restrict__ b_phi2, const float* __restrict__ b_msg,
    const int4* __restrict__ metaI, const float4* __restrict__ metaF,
    int p0, ushort* __restrict__ payloadM,
    float* __restrict__ Hout, float* __restrict__ Vout) {

    // flat LDS: A1 phase uses stride 264 (16896); later hid stride 136 (8704)
    // + m_lds stride 132 at offset 8704 (8448) -> total 17152
    __shared__ ushort A1f[TILE * 264 + 256];
    __shared__ ushort WB[128][132];
    __shared__ float  s_bt[3][128];
    __shared__ int    s_row[TILE], s_col[TILE], s_ty[TILE], s_e2[TILE], s_vcol[TILE];
    __shared__ float  s_dist[TILE], s_dval[TILE], s_env[TILE], s_env2[TILE];
    __shared__ float  s_unit[TILE][3];

    ushort* hidp  = A1f;          // stride 136, 64 rows
    ushort* m_lds = A1f + 8704;   // stride 132, 64 rows (conflict-free scalar stores)

    const int t = threadIdx.x;
    const int gbase = blockIdx.x * TILE;   // chunk-local base

    // ---- edge meta ----
    if (MODE == 1) {
        if (t < TILE) {
            int4 mi = metaI[p0 + gbase + t];
            s_col[t] = mi.x; s_row[t] = mi.y; s_ty[t] = mi.z; s_e2[t] = mi.w;
        } else if (t < 2 * TILE) {
            int e = t - TILE;
            float4 mf = metaF[p0 + gbase + e];
            s_dist[e] = mf.x; s_dval[e] = mf.y; s_env[e] = mf.z; s_env2[e] = mf.w;
        }
    } else {
        if (t < TILE) {
            int gpos = gbase + t;
            int eid = (gpos < NEFF) ? gpos : -1;
            int row, col, ty, e2 = 0; float dval = 0.f;
            if (eid < 0)             { ty = 1; row = -1; col = 0; }
            else if (eid < E1N)      { ty = 0; row = E2d_idx[eid]; col = E2d_idx[E1N + eid]; e2 = eid; }
            else if (eid < E1N + NN) { ty = 1; int jj = eid - E1N; row = jj; col = jj + NN; }
            else { ty = 2; int g2 = eid - E1N - NN;
                   row = Edist_idx[g2]; col = Edist_idx[E2N + g2]; dval = Edist_val[g2]; }
            int rs = (row < 0) ? 0 : row;
            float prx = Z[rs * 3], pry = Z[rs * 3 + 1], prz = Z[rs * 3 + 2];
            float pcx, pcy, pcz;
            if (col < NN) { pcx = Z[col * 3]; pcy = Z[col * 3 + 1]; pcz = Z[col * 3 + 2]; }
            else { int c = col - NN; pcx = Z3d[c * 3]; pcy = Z3d[c * 3 + 1]; pcz = Z3d[c * 3 + 2]; }
            float dx = prx - pcx, dy = pry - pcy, dz = prz - pcz;
            float dist = sqrtf(dx * dx + dy * dy + dz * dz + 1e-8f);
            float inv = 1.0f / dist;
            s_row[t] = row; s_col[t] = col; s_ty[t] = ty; s_e2[t] = e2;
            s_vcol[t] = (col < NN) ? col : -1;
            s_unit[t][0] = dx * inv; s_unit[t][1] = dy * inv; s_unit[t][2] = dz * inv;
            s_dist[t] = dist; s_dval[t] = dval;
            s_env[t] = env_of(dist); s_env2[t] = env_of(dval);
        }
    }
    for (int i = t; i < 384; i += 256) ((float*)s_bt)[i] = b_type[i];
    __syncthreads();

    // ---- phase A: stage A1 = [nodes_bf16[col] | attr] and WB <- W1c K-half 0 ----
    for (int i = t; i < TILE * 16; i += 256) {     // left 128: 16B vector gather
        int e = i >> 4, q = i & 15;
        *reinterpret_cast<uint4*>(&A1f[e * 264 + q * 8]) =
            *reinterpret_cast<const uint4*>(nodesb + (size_t)s_col[e] * 128 + q * 8);
    }
    if (MODE == 1) {
        for (int i = t; i < TILE * 128; i += 256) {  // right 128: [featT | rbf(dval)]
            int e = i >> 7, k = i & 127;
            int ty = s_ty[e];
            ushort v = 0;
            if (ty == 0) { if (k < 64) v = featTb[(size_t)s_e2[e] * 64 + k]; }
            else if (ty == 2) {
                if (k >= 64) {
                    float dd = s_dval[e] - (float)(k - 64) * RBF_STEP;
                    v = f2bf(__expf(-dd * dd * RBF_INV2W2) * s_env2[e]);
                }
            }
            A1f[e * 264 + 128 + k] = v;
        }
    } else {
        for (int i = t; i < TILE * 128; i += 256) {
            int k = i >> 6, e = i & 63;
            int ty = s_ty[e];
            float v = 0.f;
            if (ty == 0) { if (k < 64) v = E2d_feat[(size_t)k * E1N + s_e2[e]]; }
            else if (ty == 2) {
                if (k >= 64) {
                    float dd = s_dval[e] - (float)(k - 64) * RBF_STEP;
                    v = __expf(-dd * dd * RBF_INV2W2) * s_env2[e];
                }
            }
            A1f[e * 264 + 128 + k] = f2bf(v);
        }
    }
    for (int i = t; i < 128 * 16; i += 256) {      // WB <- W1c[:, 0:128]
        int n = i >> 4, q = i & 15;
        *reinterpret_cast<uint4*>(&WB[n][q * 8]) =
            *reinterpret_cast<const uint4*>(W1c + (size_t)n * 256 + q * 8);
    }
    __syncthreads();

    const int w  = t >> 6, lane = t & 63;
    const int mh = w >> 1, nh = w & 1;           // wave: 32 edges x 64 channels
    const int lr = lane >> 4, lc = lane & 15;
    const int ar0 = mh * 32 + lc;

    // ---- wd A-fragments in-register: rbf(dist) for edges ar0, ar0+16 ----
    bf16x8 ra0[2], ra1[2];   // [ks]
    {
        float dA = s_dist[ar0],      eA = s_env[ar0];
        float dB = s_dist[ar0 + 16], eB = s_env[ar0 + 16];
#pragma unroll
        for (int ks = 0; ks < 2; ++ks)
#pragma unroll
            for (int j = 0; j < 8; ++j) {
                float c  = (float)(ks * 32 + lr * 8 + j) * RBF_STEP;
                float tA = dA - c, tB = dB - c;
                ra0[ks][j] = (short)f2bf(__expf(-tA * tA * RBF_INV2W2) * eA);
                ra1[ks][j] = (short)f2bf(__expf(-tB * tB * RBF_INV2W2) * eB);
            }
    }

    // ---- phi1: (64 x 256) @ W1c^T -> silu -> hid bf16 (B staged in LDS, 2 halves) ----
    f32x4 acc[2][4];
#pragma unroll
    for (int mt = 0; mt < 2; ++mt)
#pragma unroll
        for (int nt = 0; nt < 4; ++nt) acc[mt][nt] = (f32x4){0.f, 0.f, 0.f, 0.f};
#pragma unroll
    for (int ks = 0; ks < 4; ++ks) {
        bf16x8 a0 = *reinterpret_cast<const bf16x8*>(&A1f[ar0 * 264 + ks * 32 + lr * 8]);
        bf16x8 a1 = *reinterpret_cast<const bf16x8*>(&A1f[(ar0 + 16) * 264 + ks * 32 + lr * 8]);
#pragma unroll
        for (int nt = 0; nt < 4; ++nt) {
            int n = nh * 64 + nt * 16 + lc;
            bf16x8 b = *reinterpret_cast<const bf16x8*>(&WB[n][ks * 32 + lr * 8]);
            acc[0][nt] = __builtin_amdgcn_mfma_f32_16x16x32_bf16(a0, b, acc[0][nt], 0, 0, 0);
            acc[1][nt] = __builtin_amdgcn_mfma_f32_16x16x32_bf16(a1, b, acc[1][nt], 0, 0, 0);
        }
    }
    __syncthreads();
    for (int i = t; i < 128 * 16; i += 256) {      // WB <- W1c[:, 128:256]
        int n = i >> 4, q = i & 15;
        *reinterpret_cast<uint4*>(&WB[n][q * 8]) =
            *reinterpret_cast<const uint4*>(W1c + (size_t)n * 256 + 128 + q * 8);
    }
    __syncthreads();
#pragma unroll
    for (int ks = 4; ks < 8; ++ks) {
        bf16x8 a0 = *reinterpret_cast<const bf16x8*>(&A1f[ar0 * 264 + ks * 32 + lr * 8]);
        bf16x8 a1 = *reinterpret_cast<const bf16x8*>(&A1f[(ar0 + 16) * 264 + ks * 32 + lr * 8]);
#pragma unroll
        for (int nt = 0; nt < 4; ++nt) {
            int n = nh * 64 + nt * 16 + lc;
            bf16x8 b = *reinterpret_cast<const bf16x8*>(&WB[n][(ks - 4) * 32 + lr * 8]);
            acc[0][nt] = __builtin_amdgcn_mfma_f32_16x16x32_bf16(a0, b, acc[0][nt], 0, 0, 0);
            acc[1][nt] = __builtin_amdgcn_mfma_f32_16x16x32_bf16(a1, b, acc[1][nt], 0, 0, 0);
        }
    }
    __syncthreads();   // all A1 + WB reads complete

    // ---- silu -> hid; stage WB <- W2b slice for c=0 ----
#pragma unroll
    for (int mt = 0; mt < 2; ++mt)
#pragma unroll
        for (int nt = 0; nt < 4; ++nt)
#pragma unroll
            for (int r = 0; r < 4; ++r) {
                int e  = mh * 32 + mt * 16 + lr * 4 + r;
                int ch = nh * 64 + nt * 16 + lc;
                float x = acc[mt][nt][r] + s_bt[s_ty[e]][ch];
                hidp[e * 136 + ch] = f2bf(x / (1.0f + __expf(-x)));
            }
    for (int i = t; i < 128 * 16; i += 256) {
        int n = i >> 4, q = i & 15;
        *reinterpret_cast<uint4*>(&WB[n][q * 8]) =
            *reinterpret_cast<const uint4*>(W2b + (size_t)n * 128 + q * 8);
    }
    __syncthreads();

    // ---- hoist hid A-fragments to registers (shared across the 3 c-chunks) ----
    bf16x8 ha0[4], ha1[4];
#pragma unroll
    for (int ks = 0; ks < 4; ++ks) {
        ha0[ks] = *reinterpret_cast<const bf16x8*>(&hidp[ar0 * 136 + ks * 32 + lr * 8]);
        ha1[ks] = *reinterpret_cast<const bf16x8*>(&hidp[(ar0 + 16) * 136 + ks * 32 + lr * 8]);
    }

    // ---- phi2 + wd in 3 channel-chunks of 128; m = phi*wd; emit ----
    f32x4 vgr[2][4];
#pragma unroll
    for (int c = 0; c < 3; ++c) {
        f32x4 p[2][4], g[2][4];
#pragma unroll
        for (int mt = 0; mt < 2; ++mt)
#pragma unroll
            for (int nt = 0; nt < 4; ++nt) {
                p[mt][nt] = (f32x4){0.f, 0.f, 0.f, 0.f};
                g[mt][nt] = (f32x4){0.f, 0.f, 0.f, 0.f};
            }
#pragma unroll
        for (int ks = 0; ks < 4; ++ks) {
#pragma unroll
            for (int nt = 0; nt < 4; ++nt) {
                int n = nh * 64 + nt * 16 + lc;
                bf16x8 b = *reinterpret_cast<const bf16x8*>(&WB[n][ks * 32 + lr * 8]);
                p[0][nt] = __builtin_amdgcn_mfma_f32_16x16x32_bf16(ha0[ks], b, p[0][nt], 0, 0, 0);
                p[1][nt] = __builtin_amdgcn_mfma_f32_16x16x32_bf16(ha1[ks], b, p[1][nt], 0, 0, 0);
            }
        }
#pragma unroll
        for (int ks = 0; ks < 2; ++ks) {
#pragma unroll
            for (int nt = 0; nt < 4; ++nt) {
                int n = c * 128 + nh * 64 + nt * 16 + lc;
                bf16x8 b = *reinterpret_cast<const bf16x8*>(Wmb + (size_t)n * 64 + ks * 32 + lr * 8);
                g[0][nt] = __builtin_amdgcn_mfma_f32_16x16x32_bf16(ra0[ks], b, g[0][nt], 0, 0, 0);
                g[1][nt] = __builtin_amdgcn_mfma_f32_16x16x32_bf16(ra1[ks], b, g[1][nt], 0, 0, 0);
            }
        }
        __syncthreads();               // WB reads for this c done; prev m_lds copy done
        if (c < 2) {                   // stage next c's W2b slice (overlaps epilogue)
            for (int i = t; i < 128 * 16; i += 256) {
                int n = i >> 4, q = i & 15;
                *reinterpret_cast<uint4*>(&WB[n][q * 8]) =
                    *reinterpret_cast<const uint4*>(W2b + (size_t)((c + 1) * 128 + n) * 128 + q * 8);
            }
        }
#pragma unroll
        for (int mt = 0; mt < 2; ++mt)
#pragma unroll
            for (int nt = 0; nt < 4; ++nt) {
                int d  = nh * 64 + nt * 16 + lc;
                float b2 = b_phi2[c * 128 + d];
                float bm = b_msg[c * 128 + d];
#pragma unroll
                for (int r = 0; r < 4; ++r) {
                    int e = mh * 32 + mt * 16 + lr * 4 + r;
                    float m = (p[mt][nt][r] + b2) * (g[mt][nt][r] + bm);
                    if (MODE == 1) {
                        m_lds[e * 132 + d] = f2bf(m);
                    } else {
                        int row = s_row[e];
                        if (c == 0) {
                            if (row >= 0) unsafeAtomicAdd(&Hout[(size_t)row * 128 + d], m);
                        } else if (c == 1) {
                            vgr[mt][nt][r] = m;
                        } else if (row >= 0) {
                            float vgv = vgr[mt][nt][r];
                            int vc = s_vcol[e];
                            float vx = 0.f, vy = 0.f, vz = 0.f;
                            if (vc >= 0) {
                                const float* vp = V + ((size_t)vc * 128 + d) * 3;
                                vx = vp[0]; vy = vp[1]; vz = vp[2];
                            }
                            float* vo = Vout + ((size_t)row * 128 + d) * 3;
                            unsafeAtomicAdd(vo + 0, vx * vgv + s_unit[e][0] * m);
                            unsafeAtomicAdd(vo + 1, vy * vgv + s_unit[e][1] * m);
                            unsafeAtomicAdd(vo + 2, vz * vgv + s_unit[e][2] * m);
                        }
                    }
                }
            }
        __syncthreads();               // m_lds complete + WB(c+1) staged
        if (MODE == 1) {
            // coalesced copy m_lds[64][132] bf16 -> payloadM (8B units, full lines)
            for (int i = t; i < 2048; i += 256) {
                int e = i >> 5, q = i & 31;
                *reinterpret_cast<uint2*>(payloadM + (size_t)(gbase + e) * 384 + c * 128 + q * 4) =
                    *reinterpret_cast<const uint2*>(m_lds + e * 132 + q * 4);
            }
        }
    }
}

// ---------------- reduce: unrolled MLP accumulation of payload into output ----------------
__global__ __launch_bounds__(256) void reduce_kernel(
    const ushort* __restrict__ payloadM, const float4* __restrict__ payloadU,
    const float* __restrict__ V, const int* __restrict__ start,
    const int* __restrict__ chunk_r0, int ci, int p0, int p1,
    float* __restrict__ Hout, float* __restrict__ Vout) {
    const int t = threadIdx.x;
    const int rbase = chunk_r0[ci] + blockIdx.x * 8;
    const bool hside = (t < 128);
    const int d = hside ? t : (t - 128);
    for (int nr = 0; nr < 8; ++nr) {
        int r = rbase + nr;
        if (r >= NN) return;
        int s0 = start[r], s1 = start[r + 1];
        if (s0 >= p1) return;
        int a = (s0 > p0) ? s0 : p0;
        int b = (s1 < p1) ? s1 : p1;
        if (a >= b) continue;
        int n = b - a;
        if (hside) {
            const ushort* base = payloadM + (size_t)(a - p0) * 384 + d;
            float a0 = 0.f, a1 = 0.f, a2 = 0.f, a3 = 0.f;
            int i = 0;
            for (; i + 4 <= n; i += 4) {
                a0 += bf2f(base[(size_t)i * 384]);
                a1 += bf2f(base[(size_t)(i + 1) * 384]);
                a2 += bf2f(base[(size_t)(i + 2) * 384]);
                a3 += bf2f(base[(size_t)(i + 3) * 384]);
            }
            for (; i < n; ++i) a0 += bf2f(base[(size_t)i * 384]);
            float acc = (a0 + a1) + (a2 + a3);
            float* ptr = &Hout[(size_t)r * 128 + d];
            float o = *ptr + acc;
            if (s1 <= p1) o = fminf(fmaxf(o, -100.f), 100.f);
            *ptr = o;
        } else {
            const ushort* base = payloadM + (size_t)(a - p0) * 384;
            const float4* ub = payloadU + a;
            float ax = 0.f, ay = 0.f, az = 0.f;
            float bx = 0.f, by = 0.f, bz = 0.f;
            int i = 0;
            for (; i + 2 <= n; i += 2) {
                const ushort* pm0 = base + (size_t)i * 384;
                const ushort* pm1 = base + (size_t)(i + 1) * 384;
                float vg0 = bf2f(pm0[128 + d]), rg0 = bf2f(pm0[256 + d]);
                float vg1 = bf2f(pm1[128 + d]), rg1 = bf2f(pm1[256 + d]);
                float4 u0 = ub[i];
                float4 u1 = ub[i + 1];
                int vc0 = __float_as_int(u0.w);
                int vc1 = __float_as_int(u1.w);
                if (vc0 >= 0) {
                    const float* vp = V + (size_t)vc0 * 384 + d * 3;
                    ax += vg0 * vp[0]; ay += vg0 * vp[1]; az += vg0 * vp[2];
                }
                if (vc1 >= 0) {
                    const float* vp = V + (size_t)vc1 * 384 + d * 3;
                    bx += vg1 * vp[0]; by += vg1 * vp[1]; bz += vg1 * vp[2];
                }
                ax += rg0 * u0.x; ay += rg0 * u0.y; az += rg0 * u0.z;
                bx += rg1 * u1.x; by += rg1 * u1.y; bz += rg1 * u1.z;
            }
            if (i < n) {
                const ushort* pm0 = base + (size_t)i * 384;
                float vg0 = bf2f(pm0[128 + d]), rg0 = bf2f(pm0[256 + d]);
                float4 u0 = ub[i];
                int vc0 = __float_as_int(u0.w);
                if (vc0 >= 0) {
                    const float* vp = V + (size_t)vc0 * 384 + d * 3;
                    ax += vg0 * vp[0]; ay += vg0 * vp[1]; az += vg0 * vp[2];
                }
                ax += rg0 * u0.x; ay += rg0 * u0.y; az += rg0 * u0.z;
            }
            ax += bx; ay += by; az += bz;
            float* vo = Vout + (size_t)r * 384 + d * 3;
            float ox = vo[0] + ax, oy = vo[1] + ay, oz = vo[2] + az;
            if (s1 <= p1) {
                ox = fminf(fmaxf(ox, -100.f), 100.f);
                oy = fminf(fmaxf(oy, -100.f), 100.f);
                oz = fminf(fmaxf(oz, -100.f), 100.f);
            }
            vo[0] = ox; vo[1] = oy; vo[2] = oz;
        }
    }
}

extern "C" void kernel_launch(void* const* d_in, const int* in_sizes, int n_in,
                              void* d_out, int out_size, void* d_ws, size_t ws_size,
                              hipStream_t stream) {
    const float* H         = (const float*)d_in[0];
    const float* V         = (const float*)d_in[1];
    const float* Z         = (const float*)d_in[2];
    const float* H2d       = (const float*)d_in[4];
    const int*   E2d_idx   = (const int*)d_in[6];
    const float* E2d_feat  = (const float*)d_in[7];
    const float* Z3d       = (const float*)d_in[8];
    const int*   Edist_idx = (const int*)d_in[10];
    const float* Edist_val = (const float*)d_in[11];
    const float* virt      = (const float*)d_in[12];
    const float* et        = (const float*)d_in[13];
    const float* W_rbf     = (const float*)d_in[14];
    const float* W_e2d     = (const float*)d_in[15];
    const float* W_i       = (const float*)d_in[16];
    const float* W_phi1    = (const float*)d_in[17];
    const float* b_phi1    = (const float*)d_in[18];
    const float* W_phi2    = (const float*)d_in[19];
    const float* b_phi2    = (const float*)d_in[20];
    const float* W_msg     = (const float*)d_in[21];
    const float* b_msg     = (const float*)d_in[22];

    ushort* nodesb  = (ushort*)d_ws;                 // 40000*128 bf16
    ushort* W1c     = nodesb + 5120000;              // (128,256)
    ushort* W2b     = W1c + 32768;                   // (384,128)
    ushort* Wmb     = W2b + 49152;                   // (384,64)
    ushort* Wib     = Wmb + 24576;                   // (128,256)
    float*  b_type  = (float*)(Wib + 32768);         // (3,128)
    ushort* featTb  = (ushort*)(b_type + 384);       // (E1N,64) bf16 = 12.8 MB
    int*    hist    = (int*)(featTb + (size_t)E1N * 64);
    int*    cursor  = hist + NN;
    int*    start   = cursor + NN;                   // NN+1
    int*    order   = start + NN + 1;                // NPAD
    int*    chunk_r0= order + NPAD;                  // 64
    int4*   metaI   = (int4*)(((size_t)(chunk_r0 + 64) + 15) & ~(size_t)15);
    float4* metaF   = (float4*)(metaI + NPAD);
    float4* payloadU= metaF + NPAD;

    size_t fixed = (size_t)((char*)(payloadU + NPAD) - (char*)d_ws);
    size_t poff  = (fixed + 255) & ~(size_t)255;
    size_t avail = (ws_size > poff) ? (ws_size - poff) : 0;
    long long cap_ll = (long long)(avail / 768) / TILE * TILE;   // 384 bf16 per edge
    int cap = (cap_ll > (long long)NPAD) ? NPAD : (int)cap_ll;
    const bool big = (cap >= 4096);
    ushort* payloadM = (ushort*)((char*)d_ws + poff);

    float* Hout = (float*)d_out;
    float* Vout = Hout + (size_t)NN * 128;

    hipMemsetAsync(d_out, 0, (size_t)out_size * sizeof(float), stream);
    prep_kernel<<<(139648 + 255) / 256, 256, 0, stream>>>(
        W_phi1, b_phi1, W_e2d, W_rbf, W_phi2, W_msg, et, W_i,
        W1c, W2b, Wmb, b_type, Wib);
    nodes_mfma_kernel<<<(2 * NN) / 64, 256, 0, stream>>>(H, H2d, virt, Wib, nodesb);

    if (big) {
        hipMemsetAsync(hist, 0, NN * sizeof(int), stream);
        featT_kernel<<<(E1N + 63) / 64, 256, 0, stream>>>(E2d_feat, featTb);
        hist_kernel<<<(NEFF + 255) / 256, 256, 0, stream>>>(E2d_idx, Edist_idx, hist);
        scan_kernel<<<1, 1024, 0, stream>>>(hist, start, cursor);
        scatter_kernel<<<(NEFF + 255) / 256, 256, 0, stream>>>(E2d_idx, Edist_idx, cursor, order);
        meta_kernel<<<(NPAD + 255) / 256, 256, 0, stream>>>(
            order, E2d_idx, Edist_idx, Edist_val, Z, Z3d, metaI, metaF, payloadU);
        int bpc = cap / TILE;
        int nch = (NBLK + bpc - 1) / bpc;
        chunkrow_kernel<<<1, 64, 0, stream>>>(order, E2d_idx, Edist_idx, cap, nch, chunk_r0);
        int rbound = (NN < cap + 1) ? NN : (cap + 1);
        int rgrid  = (rbound + 7) / 8;
        for (int ci = 0; ci < nch; ++ci) {
            int b0 = ci * bpc;
            int nb = ((NBLK - b0) < bpc) ? (NBLK - b0) : bpc;
            int p0 = b0 * TILE;
            int p1 = p0 + nb * TILE; if (p1 > NEFF) p1 = NEFF;
            edge_kernel<1><<<nb, 256, 0, stream>>>(
                nodesb, V, Z, Z3d, E2d_idx, E2d_feat, featTb, Edist_idx, Edist_val,
                W1c, W2b, Wmb, b_type, b_phi2, b_msg, metaI, metaF, p0, payloadM,
                Hout, Vout);
            reduce_kernel<<<rgrid, 256, 0, stream>>>(payloadM, payloadU, V, start,
                                                     chunk_r0, ci, p0, p1, Hout, Vout);
        }
    } else {
        edge_kernel<0><<<NBLK, 256, 0, stream>>>(
            nodesb, V, Z, Z3d, E2d_idx, E2d_feat, featTb, Edist_idx, Edist_val,
            W1c, W2b, Wmb, b_type, b_phi2, b_msg, metaI, metaF, 0, payloadM,
            Hout, Vout);
    }
}